// Round 10
// baseline (604.330 us; speedup 1.0000x reference)
//
#include <hip/hip_runtime.h>
#include <math.h>

// Problem constants (AttentionWriter): B=8,S=1024,M=2048,D=512,H=512,NH=8,Dh=64
#define BB 8
#define SS 1024
#define MM 2048
#define DD 512
#define HH 512
#define NHEAD 8
#define DHEAD 64

typedef __attribute__((ext_vector_type(8))) short short8;
typedef __attribute__((ext_vector_type(4))) float f32x4;
typedef unsigned short us;

// bf16 split helpers (RNE)
__device__ __forceinline__ us bf_hi(float x) {
    unsigned u = __float_as_uint(x);
    return (us)((u + 0x7FFFu + ((u >> 16) & 1u)) >> 16);
}
__device__ __forceinline__ float bf_f(us h) {
    return __uint_as_float(((unsigned)h) << 16);
}
__device__ __forceinline__ void split_pack4(float a, float b, float c, float d,
                                            uint2& hp, uint2& lp) {
    us h0 = bf_hi(a), h1 = bf_hi(b), h2 = bf_hi(c), h3 = bf_hi(d);
    hp.x = (unsigned)h0 | ((unsigned)h1 << 16);
    hp.y = (unsigned)h2 | ((unsigned)h3 << 16);
    us l0 = bf_hi(a - bf_f(h0)), l1 = bf_hi(b - bf_f(h1));
    us l2 = bf_hi(c - bf_f(h2)), l3 = bf_hi(d - bf_f(h3));
    lp.x = (unsigned)l0 | ((unsigned)l1 << 16);
    lp.y = (unsigned)l2 | ((unsigned)l3 << 16);
}

// async global->LDS DMA, 16B per lane; LDS dest = wave-uniform base + lane*16
__device__ __forceinline__ void gload_lds16(const void* g, void* l) {
    __builtin_amdgcn_global_load_lds(
        (__attribute__((address_space(1))) void*)(g),
        (__attribute__((address_space(3))) void*)(l), 16, 0, 0);
}

// ---------------------------------------------------------------------------
// copy memory_bank -> out_updated AND emit bf16 hi/lo split (for Q-GEMM A)
// ---------------------------------------------------------------------------
__global__ __launch_bounds__(256) void copy_split(
    const float* __restrict__ x, float* __restrict__ cpy,
    us* __restrict__ hi, us* __restrict__ lo, int n8)
{
    const int stride = gridDim.x * 256;
    for (int i = blockIdx.x * 256 + threadIdx.x; i < n8; i += stride) {
        const float4 a = *(const float4*)(x + (size_t)i * 8);
        const float4 b = *(const float4*)(x + (size_t)i * 8 + 4);
        *(float4*)(cpy + (size_t)i * 8) = a;
        *(float4*)(cpy + (size_t)i * 8 + 4) = b;
        uint2 h0, l0, h1, l1;
        split_pack4(a.x, a.y, a.z, a.w, h0, l0);
        split_pack4(b.x, b.y, b.z, b.w, h1, l1);
        *(uint2*)(hi + (size_t)i * 8) = h0;
        *(uint2*)(hi + (size_t)i * 8 + 4) = h1;
        *(uint2*)(lo + (size_t)i * 8) = l0;
        *(uint2*)(lo + (size_t)i * 8 + 4) = l1;
    }
}

// ---------------------------------------------------------------------------
// f32 GEMM (precision-sensitive importance path ONLY); optional split-out
// ---------------------------------------------------------------------------
__global__ __launch_bounds__(256) void gemm128(
    const float* __restrict__ A, const float* __restrict__ W,
    const float* __restrict__ bias, float* __restrict__ C,
    int K, int N, int act, us* __restrict__ hi_out, us* __restrict__ lo_out)
{
    __shared__ float As[8][132];
    __shared__ float Bs[8][128];
    const int tid  = threadIdx.x;
    const int row0 = blockIdx.y * 128, col0 = blockIdx.x * 128;
    const int ty = tid >> 4, tx = tid & 15;

    const int arow = tid >> 1,  ak4  = (tid & 1) * 4;
    const int bk   = tid >> 5,  bcol = (tid & 31) * 4;

    const float* Ap = A + (size_t)(row0 + arow) * K + ak4;
    const float* Wp = W + (size_t)bk * N + col0 + bcol;

    float4 aReg = *(const float4*)Ap;
    float4 bReg = *(const float4*)Wp;

    float acc[8][8];
#pragma unroll
    for (int i = 0; i < 8; ++i)
#pragma unroll
        for (int j = 0; j < 8; ++j) acc[i][j] = 0.f;

    for (int k0 = 0; k0 < K; k0 += 8) {
        __syncthreads();
        As[ak4 + 0][arow] = aReg.x;
        As[ak4 + 1][arow] = aReg.y;
        As[ak4 + 2][arow] = aReg.z;
        As[ak4 + 3][arow] = aReg.w;
        *(float4*)&Bs[bk][bcol] = bReg;
        __syncthreads();
        if (k0 + 8 < K) {
            aReg = *(const float4*)(Ap + k0 + 8);
            bReg = *(const float4*)(Wp + (size_t)(k0 + 8) * N);
        }
#pragma unroll
        for (int kk = 0; kk < 8; ++kk) {
            float a[8], b[8];
            *(float4*)&a[0] = *(const float4*)&As[kk][ty * 8];
            *(float4*)&a[4] = *(const float4*)&As[kk][ty * 8 + 4];
            *(float4*)&b[0] = *(const float4*)&Bs[kk][tx * 4];
            *(float4*)&b[4] = *(const float4*)&Bs[kk][64 + tx * 4];
#pragma unroll
            for (int i = 0; i < 8; ++i)
#pragma unroll
                for (int j = 0; j < 8; ++j)
                    acc[i][j] = fmaf(a[i], b[j], acc[i][j]);
        }
    }

#pragma unroll
    for (int i = 0; i < 8; ++i) {
        const int r = row0 + ty * 8 + i;
#pragma unroll
        for (int half = 0; half < 2; ++half) {
            const int c = col0 + half * 64 + tx * 4;
            float4 bv = bias ? *(const float4*)&bias[c] : make_float4(0.f, 0.f, 0.f, 0.f);
            float4 v;
            v.x = acc[i][half * 4 + 0] + bv.x;
            v.y = acc[i][half * 4 + 1] + bv.y;
            v.z = acc[i][half * 4 + 2] + bv.z;
            v.w = acc[i][half * 4 + 3] + bv.w;
            if (act == 1) {
                v.x = fmaxf(v.x, 0.f); v.y = fmaxf(v.y, 0.f);
                v.z = fmaxf(v.z, 0.f); v.w = fmaxf(v.w, 0.f);
            }
            *(float4*)&C[(size_t)r * N + c] = v;
            if (hi_out) {
                uint2 hp, lp;
                split_pack4(v.x, v.y, v.z, v.w, hp, lp);
                *(uint2*)&hi_out[(size_t)r * N + c] = hp;
                *(uint2*)&lo_out[(size_t)r * N + c] = lp;
            }
        }
    }
}

// ---------------------------------------------------------------------------
// batched transpose+split of [512][512] f32 weights -> [n][k] bf16 hi/lo
// ---------------------------------------------------------------------------
struct TSB {
    const float* src[6];
    us* dh[6];
    us* dl[6];
};
__global__ __launch_bounds__(256) void transpose_split_batch(TSB a)
{
    __shared__ float tile[32][33];
    const int tid = threadIdx.x;
    const int n0 = blockIdx.x * 32, k0 = blockIdx.y * 32;
    const int wsel = blockIdx.z;
    const float* W = a.src[wsel];
    {
        const int r = tid >> 3, c = (tid & 7) * 4;
        const float4 v = *(const float4*)(W + (size_t)(k0 + r) * 512 + n0 + c);
        tile[r][c + 0] = v.x; tile[r][c + 1] = v.y;
        tile[r][c + 2] = v.z; tile[r][c + 3] = v.w;
    }
    __syncthreads();
    {
        const int n = tid >> 3, k = (tid & 7) * 4;
        uint2 hp, lp;
        split_pack4(tile[k + 0][n], tile[k + 1][n], tile[k + 2][n], tile[k + 3][n], hp, lp);
        *(uint2*)(a.dh[wsel] + (size_t)(n0 + n) * 512 + k0 + k) = hp;
        *(uint2*)(a.dl[wsel] + (size_t)(n0 + n) * 512 + k0 + k) = lp;
    }
}

// fused bias for Q: out[n] = b_in @ Wq + bq
__global__ __launch_bounds__(256) void bias_fuse(
    const float* __restrict__ b_in, const float* __restrict__ Wq,
    const float* __restrict__ bq, float* __restrict__ out)
{
    const int n = blockIdx.x * 256 + threadIdx.x;
    float a = bq[n];
    for (int k = 0; k < 512; ++k) a = fmaf(b_in[k], Wq[(size_t)k * 512 + n], a);
    out[n] = a;
}

// concat bk|bv -> bkv[1024]
__global__ __launch_bounds__(256) void concat_bias(
    const float* __restrict__ a, const float* __restrict__ b, float* __restrict__ o)
{
    const int i = blockIdx.x * 256 + threadIdx.x;
    o[i] = (i < 512) ? a[i] : b[i - 512];
}

// ---------------------------------------------------------------------------
// OLD split-bf16 MFMA GEMM (f32 A split in-kernel) — kept ONLY for tiny winq
// ---------------------------------------------------------------------------
__global__ __launch_bounds__(256) void gemm_mfma(
    const float* __restrict__ A,
    const us* __restrict__ Bh, const us* __restrict__ Bl,
    const float* __restrict__ bias, float* __restrict__ C, int K, int N)
{
    __shared__ us sm[32768];
    us* sAh = sm;            us* sAl = sm + 8192;
    us* sBh = sm + 16384;    us* sBl = sm + 24576;
    const int tid = threadIdx.x, lane = tid & 63;
    const int wid = tid >> 6, wm = wid >> 1, wn = wid & 1;
    const int m0 = blockIdx.y * 128, n0 = blockIdx.x * 128;
    const int fr = lane & 15, fq4 = lane >> 4;
    f32x4 acc[4][4];
#pragma unroll
    for (int i = 0; i < 4; ++i)
#pragma unroll
        for (int j = 0; j < 4; ++j)
#pragma unroll
            for (int r = 0; r < 4; ++r) acc[i][j][r] = 0.f;
    const int ar = tid >> 4;
    const int ak = (tid & 15) * 4;
    int bsrow[4], bsf[4], bsoff[4];
#pragma unroll
    for (int it = 0; it < 4; ++it) {
        const int s = tid + 256 * it;
        bsrow[it] = s >> 3;
        bsf[it] = s & 7;
        bsoff[it] = bsrow[it] * 64 + ((bsf[it] ^ (bsrow[it] & 7)) << 3);
    }
    for (int k0 = 0; k0 < K; k0 += 64) {
        __syncthreads();
#pragma unroll
        for (int p = 0; p < 8; ++p) {
            const int r = p * 16 + ar;
            const float4 av = *(const float4*)(A + (size_t)(m0 + r) * K + k0 + ak);
            const int aoff = r * 128 + (((ak >> 3) ^ (r & 7)) << 4) + ((tid & 1) << 3);
            uint2 hp, lp;
            split_pack4(av.x, av.y, av.z, av.w, hp, lp);
            *(uint2*)((char*)sAh + aoff) = hp;
            *(uint2*)((char*)sAl + aoff) = lp;
        }
#pragma unroll
        for (int it = 0; it < 4; ++it) {
            const size_t bo = (size_t)(n0 + bsrow[it]) * K + k0 + bsf[it] * 8;
            *(uint4*)(sBh + bsoff[it]) = *(const uint4*)(Bh + bo);
            *(uint4*)(sBl + bsoff[it]) = *(const uint4*)(Bl + bo);
        }
        __syncthreads();
#pragma unroll
        for (int ks = 0; ks < 2; ++ks) {
            short8 afh[4], afl[4], bfh[4], bfl[4];
#pragma unroll
            for (int i = 0; i < 4; ++i) {
                const int row = wm * 64 + i * 16 + fr;
                const int off = row * 128 + (((ks * 4 + fq4) ^ (row & 7)) << 4);
                afh[i] = *(const short8*)((const char*)sAh + off);
                afl[i] = *(const short8*)((const char*)sAl + off);
            }
#pragma unroll
            for (int j = 0; j < 4; ++j) {
                const int row = wn * 64 + j * 16 + fr;
                const int off = row * 128 + (((ks * 4 + fq4) ^ (row & 7)) << 4);
                bfh[j] = *(const short8*)((const char*)sBh + off);
                bfl[j] = *(const short8*)((const char*)sBl + off);
            }
#pragma unroll
            for (int i = 0; i < 4; ++i)
#pragma unroll
                for (int j = 0; j < 4; ++j) {
                    acc[i][j] = __builtin_amdgcn_mfma_f32_16x16x32_bf16(afh[i], bfh[j], acc[i][j], 0, 0, 0);
                    acc[i][j] = __builtin_amdgcn_mfma_f32_16x16x32_bf16(afh[i], bfl[j], acc[i][j], 0, 0, 0);
                    acc[i][j] = __builtin_amdgcn_mfma_f32_16x16x32_bf16(afl[i], bfh[j], acc[i][j], 0, 0, 0);
                }
        }
    }
#pragma unroll
    for (int j = 0; j < 4; ++j) {
        const int col = n0 + wn * 64 + j * 16 + fr;
        const float bj = bias ? bias[col] : 0.f;
#pragma unroll
        for (int i = 0; i < 4; ++i)
#pragma unroll
            for (int r = 0; r < 4; ++r) {
                const int row = m0 + wm * 64 + i * 16 + fq4 * 4 + r;
                C[(size_t)row * N + col] = acc[i][j][r] + bj;
            }
    }
}

// ---------------------------------------------------------------------------
// PRE-SPLIT MFMA GEMM: A and B both pre-split bf16 hi/lo; all four operand
// arrays staged via global_load_lds (no VGPR staging, no split VALU).
// Wave w stages array w (Ah|Al|Bh|Bl), 16x 1KB issues per K-step; XOR frag
// swizzle applied by pre-swizzling the per-lane GLOBAL source address
// (R9-validated). Tile 128x128, BK=64, 4 waves, 2 barriers/K-step.
// ---------------------------------------------------------------------------
#define GEMM_PS_BODY(K_)                                                            \
    __shared__ us sm[32768];                                                        \
    us* sAh = sm;            us* sAl = sm + 8192;                                   \
    us* sBh = sm + 16384;    us* sBl = sm + 24576;                                  \
    const int tid = threadIdx.x, lane = tid & 63;                                   \
    const int wid = tid >> 6, wm = wid >> 1, wn = wid & 1;                          \
    const int m0 = blockIdx.y * 128, n0 = blockIdx.x * 128;                         \
    const int fr = lane & 15, fq4 = lane >> 4;                                      \
    f32x4 acc[4][4];                                                                \
    _Pragma("unroll")                                                               \
    for (int i = 0; i < 4; ++i)                                                     \
        _Pragma("unroll")                                                           \
        for (int j = 0; j < 4; ++j)                                                 \
            _Pragma("unroll")                                                       \
            for (int r = 0; r < 4; ++r) acc[i][j][r] = 0.f;                         \
    const int fp = lane & 7, rsub = lane >> 3;                                      \
    const us* gsrc = (wid == 0) ? Ah : (wid == 1) ? Al : (wid == 2) ? Bh : Bl;      \
    const int grow0 = (wid < 2) ? m0 : n0;                                          \
    const int grs = (wid < 2) ? rsA : (K_);                                         \
    us* lbase = sm + wid * 8192;                                                    \
    for (int k0 = 0; k0 < (K_); k0 += 64) {                                         \
        __syncthreads();                                                            \
        _Pragma("unroll")                                                           \
        for (int i = 0; i < 16; ++i) {                                              \
            const int row = i * 8 + rsub;                                           \
            const us* g = gsrc + (size_t)(grow0 + row) * grs + k0 +                 \
                          ((fp ^ (row & 7)) << 3);                                  \
            gload_lds16(g, lbase + i * 512);                                        \
        }                                                                           \
        __syncthreads();                                                            \
        _Pragma("unroll")                                                           \
        for (int ks = 0; ks < 2; ++ks) {                                            \
            short8 afh[4], afl[4], bfh[4], bfl[4];                                  \
            _Pragma("unroll")                                                       \
            for (int i = 0; i < 4; ++i) {                                           \
                const int row = wm * 64 + i * 16 + fr;                              \
                const int off = row * 128 + (((ks * 4 + fq4) ^ (row & 7)) << 4);    \
                afh[i] = *(const short8*)((const char*)sAh + off);                  \
                afl[i] = *(const short8*)((const char*)sAl + off);                  \
            }                                                                       \
            _Pragma("unroll")                                                       \
            for (int j = 0; j < 4; ++j) {                                           \
                const int row = wn * 64 + j * 16 + fr;                              \
                const int off = row * 128 + (((ks * 4 + fq4) ^ (row & 7)) << 4);    \
                bfh[j] = *(const short8*)((const char*)sBh + off);                  \
                bfl[j] = *(const short8*)((const char*)sBl + off);                  \
            }                                                                       \
            _Pragma("unroll")                                                       \
            for (int i = 0; i < 4; ++i)                                             \
                _Pragma("unroll")                                                   \
                for (int j = 0; j < 4; ++j) {                                       \
                    acc[i][j] = __builtin_amdgcn_mfma_f32_16x16x32_bf16(afh[i], bfh[j], acc[i][j], 0, 0, 0); \
                    acc[i][j] = __builtin_amdgcn_mfma_f32_16x16x32_bf16(afh[i], bfl[j], acc[i][j], 0, 0, 0); \
                    acc[i][j] = __builtin_amdgcn_mfma_f32_16x16x32_bf16(afl[i], bfh[j], acc[i][j], 0, 0, 0); \
                }                                                                   \
        }                                                                           \
    }

__global__ __launch_bounds__(256) void gemm_mfma_ps(
    const us* __restrict__ Ah, const us* __restrict__ Al, int rsA,
    const us* __restrict__ Bh, const us* __restrict__ Bl,
    const float* __restrict__ bias, float* __restrict__ C,
    int K, int N, const float* __restrict__ rowscale, int rsdiv)
{
    GEMM_PS_BODY(K)
#pragma unroll
    for (int j = 0; j < 4; ++j) {
        const int col = n0 + wn * 64 + j * 16 + fr;
        const float bj = bias ? bias[col] : 0.f;
#pragma unroll
        for (int i = 0; i < 4; ++i) {
#pragma unroll
            for (int r = 0; r < 4; ++r) {
                const int row = m0 + wm * 64 + i * 16 + fq4 * 4 + r;
                float v = acc[i][j][r] + bj;
                if (rowscale) v *= rowscale[row / rsdiv];
                C[(size_t)row * N + col] = v;
            }
        }
    }
}

// KV variant: N=1024 (Wk|Wv). cols<512 -> K rows [B*S][512] bf16 hi/lo;
// cols>=512 -> V TRANSPOSED [B][512 d][1024 s] bf16 hi/lo.
__global__ __launch_bounds__(256) void gemm_mfma_kv_ps(
    const us* __restrict__ Ah, const us* __restrict__ Al, int rsA,
    const us* __restrict__ Bh, const us* __restrict__ Bl,
    const float* __restrict__ bias,
    us* __restrict__ Kh, us* __restrict__ Kl,
    us* __restrict__ Vth, us* __restrict__ Vtl, int K)
{
    GEMM_PS_BODY(K)
    if (n0 < 512) {
#pragma unroll
        for (int j = 0; j < 4; ++j) {
            const int col = n0 + wn * 64 + j * 16 + fr;
            const float bj = bias[col];
#pragma unroll
            for (int i = 0; i < 4; ++i)
#pragma unroll
                for (int r = 0; r < 4; ++r) {
                    const int row = m0 + wm * 64 + i * 16 + fq4 * 4 + r;
                    const float v = acc[i][j][r] + bj;
                    const us hv = bf_hi(v);
                    Kh[(size_t)row * 512 + col] = hv;
                    Kl[(size_t)row * 512 + col] = bf_hi(v - bf_f(hv));
                }
        }
    } else {
#pragma unroll
        for (int j = 0; j < 4; ++j) {
            const int col = n0 + wn * 64 + j * 16 + fr;
            const float bj = bias[col];
            const int d = col - 512;
#pragma unroll
            for (int i = 0; i < 4; ++i) {
                const int row0 = m0 + wm * 64 + i * 16 + fq4 * 4;
                uint2 hp, lp;
                split_pack4(acc[i][j][0] + bj, acc[i][j][1] + bj,
                            acc[i][j][2] + bj, acc[i][j][3] + bj, hp, lp);
                const size_t vo = ((size_t)(row0 >> 10) * 512 + d) * 1024 + (row0 & 1023);
                *(uint2*)(Vth + vo) = hp;
                *(uint2*)(Vtl + vo) = lp;
            }
        }
    }
}

// ---------------------------------------------------------------------------
// MFMA flash attention v4.1 (R9 structure): DMA-staged K/V, spill-free.
// Epilogue now emits the output PRE-SPLIT (hi/lo bf16) for the Wo GEMM,
// written to a dedicated buffer (mbh/mbl, dead after Q-GEMM) — NOT qhb,
// whose per-head byte footprints would race across blocks.
// ---------------------------------------------------------------------------
__global__ __launch_bounds__(256) void attn_mfma(
    const float* __restrict__ qh,
    const us* __restrict__ Kh, const us* __restrict__ Kl,
    const us* __restrict__ Vth, const us* __restrict__ Vtl,
    us* __restrict__ aoh, us* __restrict__ aol)
{
    __shared__ us sm[24576];    // sKh|sKl|sVh|sVl (4096 us each) | sPh|sPl
    __shared__ float sSc[64];
    us* sKh = sm;            us* sKl = sm + 4096;
    us* sVh = sm + 8192;     us* sVl = sm + 12288;
    us* sPh = sm + 16384;    us* sPl = sm + 20480;

    const int tid = threadIdx.x, lane = tid & 63, w = tid >> 6;
    const int fr = lane & 15, fq4 = lane >> 4;

    // XCD swizzle: 32 blocks sharing one (b,h) K/V slice land on one XCD
    const int wg = blockIdx.x;              // 0..2047
    const int xcd = wg & 7, ix = wg >> 3;   // ix 0..255
    const int mt = ix & 31;
    const int pair = xcd + 8 * (ix >> 5);   // 0..63
    const int h = pair & 7, b = pair >> 3;
    const int m0 = mt * 64;

    const float* Qg = qh + ((size_t)(b * MM + m0)) * HH + h * DHEAD;
    const us* Kgh = Kh + ((size_t)b * SS) * 512 + h * DHEAD;
    const us* Kgl = Kl + ((size_t)b * SS) * 512 + h * DHEAD;
    const us* Vgh = Vth + ((size_t)b * 512 + h * DHEAD) * 1024;
    const us* Vgl = Vtl + ((size_t)b * 512 + h * DHEAD) * 1024;
    us* Oh = aoh + ((size_t)(b * MM + m0)) * 512 + h * DHEAD;
    us* Ol = aol + ((size_t)(b * MM + m0)) * 512 + h * DHEAD;

    // ---- Q fragments in registers (pre-scaled by 1/8), hi/lo split
    short8 qfh[2], qfl[2];   // [ks]
#pragma unroll
    for (int ks = 0; ks < 2; ++ks) {
        const float* qp = Qg + (size_t)(w * 16 + fr) * HH + ks * 32 + fq4 * 8;
        const float4 u0 = *(const float4*)qp;
        const float4 u1 = *(const float4*)(qp + 4);
        float v[8] = {u0.x, u0.y, u0.z, u0.w, u1.x, u1.y, u1.z, u1.w};
#pragma unroll
        for (int e = 0; e < 8; ++e) {
            const float x = v[e] * 0.125f;
            const us hb = bf_hi(x);
            qfh[ks][e] = (short)hb;
            qfl[ks][e] = (short)bf_hi(x - bf_f(hb));
        }
    }

    // DMA staging: wave w stages array w; lane -> (row = i*8+lane>>3, fp=lane&7)
    const int fp = lane & 7;
    const int rsub = lane >> 3;
    const bool isK = (w < 2);
    const us* gA = (w == 0) ? Kgh : (w == 1) ? Kgl : (w == 2) ? Vgh : Vgl;
    us* lbase = sm + w * 4096;

    f32x4 oacc[4];
#pragma unroll
    for (int j = 0; j < 4; ++j)
#pragma unroll
        for (int r = 0; r < 4; ++r) oacc[j][r] = 0.f;
    float mrun = -1e30f, lrun = 0.f;

    for (int t = 0; t < SS / 64; ++t) {
        __syncthreads();                 // prev chunk's LDS reads done
        if (isK) {
#pragma unroll
            for (int i = 0; i < 8; ++i) {
                const int row = i * 8 + rsub;
                const us* g = gA + (size_t)(t * 64 + row) * 512 + ((fp ^ (row & 7)) << 3);
                gload_lds16(g, lbase + i * 512);
            }
        } else {
#pragma unroll
            for (int i = 0; i < 8; ++i) {
                const int row = i * 8 + rsub;   // row = d
                const us* g = gA + (size_t)row * 1024 + t * 64 + ((fp ^ (row & 7)) << 3);
                gload_lds16(g, lbase + i * 512);
            }
        }
        __syncthreads();                 // drains vmcnt -> staging visible

        // ---- QK^T (swapped): stt[fs] = K-slice x Q^T; C: row=s, col=q=fr
        f32x4 stt[4];
#pragma unroll
        for (int fs = 0; fs < 4; ++fs)
#pragma unroll
            for (int r = 0; r < 4; ++r) stt[fs][r] = 0.f;
#pragma unroll
        for (int ks = 0; ks < 2; ++ks) {
            short8 kfh[4], kfl[4];
#pragma unroll
            for (int fs = 0; fs < 4; ++fs) {
                const int row = fs * 16 + fr;
                const int off = row * 128 + (((ks * 4 + fq4) ^ (row & 7)) << 4);
                kfh[fs] = *(const short8*)((const char*)sKh + off);
                kfl[fs] = *(const short8*)((const char*)sKl + off);
            }
#pragma unroll
            for (int fs = 0; fs < 4; ++fs) {
                stt[fs] = __builtin_amdgcn_mfma_f32_16x16x32_bf16(kfh[fs], qfh[ks], stt[fs], 0, 0, 0);
                stt[fs] = __builtin_amdgcn_mfma_f32_16x16x32_bf16(kfh[fs], qfl[ks], stt[fs], 0, 0, 0);
                stt[fs] = __builtin_amdgcn_mfma_f32_16x16x32_bf16(kfl[fs], qfh[ks], stt[fs], 0, 0, 0);
            }
        }

        // ---- online softmax (q = fr; s spans 4 regs x 4 fs x 4 quarters)
        {
            float mx = stt[0][0];
#pragma unroll
            for (int fs = 0; fs < 4; ++fs)
#pragma unroll
                for (int r = 0; r < 4; ++r) mx = fmaxf(mx, stt[fs][r]);
            mx = fmaxf(mx, __shfl_xor(mx, 16));
            mx = fmaxf(mx, __shfl_xor(mx, 32));
            const float nm = fmaxf(mrun, mx);
            const float scf = __expf(mrun - nm);
            mrun = nm;
            float ps = 0.f;
#pragma unroll
            for (int fs = 0; fs < 4; ++fs)
#pragma unroll
                for (int r = 0; r < 4; ++r) {
                    const float p = __expf(stt[fs][r] - nm);
                    stt[fs][r] = p;
                    ps += p;
                }
            ps += __shfl_xor(ps, 16);
            ps += __shfl_xor(ps, 32);
            lrun = lrun * scf + ps;
            if (fq4 == 0) sSc[w * 16 + fr] = scf;
        }

        // ---- write P[q][s] hi/lo (wave-private rows, no barrier needed)
#pragma unroll
        for (int fs = 0; fs < 4; ++fs) {
            const int q = w * 16 + fr;
            const int flog = (fs << 1) | (fq4 >> 1);
            const int off = q * 128 + ((flog ^ (q & 7)) << 4) + ((fq4 & 1) << 3);
            uint2 hp, lp;
            split_pack4(stt[fs][0], stt[fs][1], stt[fs][2], stt[fs][3], hp, lp);
            *(uint2*)((char*)sPh + off) = hp;
            *(uint2*)((char*)sPl + off) = lp;
        }

        // ---- rescale oacc (q = w*16 + fq4*4 + r)
#pragma unroll
        for (int r = 0; r < 4; ++r) {
            const float scv = sSc[w * 16 + fq4 * 4 + r];
#pragma unroll
            for (int fd = 0; fd < 4; ++fd) oacc[fd][r] *= scv;
        }

        // ---- PV: oacc[fd] += P x V
#pragma unroll
        for (int ks = 0; ks < 2; ++ks) {
            short8 pfh, pfl, vfh[4], vfl[4];
            {
                const int row = w * 16 + fr;
                const int off = row * 128 + (((ks * 4 + fq4) ^ (row & 7)) << 4);
                pfh = *(const short8*)((const char*)sPh + off);
                pfl = *(const short8*)((const char*)sPl + off);
            }
#pragma unroll
            for (int fd = 0; fd < 4; ++fd) {
                const int row = fd * 16 + fr;
                const int off = row * 128 + (((ks * 4 + fq4) ^ (row & 7)) << 4);
                vfh[fd] = *(const short8*)((const char*)sVh + off);
                vfl[fd] = *(const short8*)((const char*)sVl + off);
            }
#pragma unroll
            for (int fd = 0; fd < 4; ++fd) {
                oacc[fd] = __builtin_amdgcn_mfma_f32_16x16x32_bf16(pfh, vfh[fd], oacc[fd], 0, 0, 0);
                oacc[fd] = __builtin_amdgcn_mfma_f32_16x16x32_bf16(pfh, vfl[fd], oacc[fd], 0, 0, 0);
                oacc[fd] = __builtin_amdgcn_mfma_f32_16x16x32_bf16(pfl, vfh[fd], oacc[fd], 0, 0, 0);
            }
        }
    }

    // ---- normalize + store PRE-SPLIT (hi/lo)
    if (fq4 == 0) sSc[w * 16 + fr] = lrun;
#pragma unroll
    for (int r = 0; r < 4; ++r) {
        const float inv = 1.0f / sSc[w * 16 + fq4 * 4 + r];
        const int q = w * 16 + fq4 * 4 + r;
#pragma unroll
        for (int fd = 0; fd < 4; ++fd) {
            const float v = oacc[fd][r] * inv;
            const us hv = bf_hi(v);
            Oh[(size_t)q * 512 + fd * 16 + fr] = hv;
            Ol[(size_t)q * 512 + fd * 16 + fr] = bf_hi(v - bf_f(hv));
        }
    }
}

// imp[row] = sigmoid(dot(h1[row,0:256], Wi2) + bi2); one wave per row
__global__ __launch_bounds__(256) void imp_kernel(
    const float* __restrict__ h1, const float* __restrict__ Wi2,
    const float* __restrict__ bi2, float* __restrict__ imp)
{
    const int wv = threadIdx.x >> 6, lane = threadIdx.x & 63;
    const int row = blockIdx.x * 4 + wv;
    const float4 hv = *(const float4*)(h1 + (size_t)row * 256 + lane * 4);
    const float4 wvv = *(const float4*)(Wi2 + lane * 4);
    float s = hv.x * wvv.x + hv.y * wvv.y + hv.z * wvv.z + hv.w * wvv.w;
#pragma unroll
    for (int m = 1; m < 64; m <<= 1) s += __shfl_xor(s, m);
    if (lane == 0) imp[row] = 1.0f / (1.0f + expf(-(s + bi2[0])));
}

// per batch: mean(imp), last index with imp>0.5, exists
__global__ __launch_bounds__(256) void impstats_kernel(
    const float* __restrict__ imp, float* __restrict__ imp_mean,
    int* __restrict__ s_star, int* __restrict__ exists)
{
    const int b = blockIdx.x, tid = threadIdx.x;
    float sum = 0.f; int last = -1;
    for (int s = tid; s < SS; s += 256) {
        const float v = imp[b * SS + s];
        sum += v;
        if (v > 0.5f) last = s;
    }
#pragma unroll
    for (int m = 1; m < 64; m <<= 1) {
        sum += __shfl_xor(sum, m);
        last = max(last, __shfl_xor(last, m));
    }
    __shared__ float ssum[4]; __shared__ int slast[4];
    if ((tid & 63) == 0) { ssum[tid >> 6] = sum; slast[tid >> 6] = last; }
    __syncthreads();
    if (tid == 0) {
        const float t = ssum[0] + ssum[1] + ssum[2] + ssum[3];
        const int ml = max(max(slast[0], slast[1]), max(slast[2], slast[3]));
        imp_mean[b] = t / (float)SS;
        exists[b] = (ml >= 0) ? 1 : 0;
        s_star[b] = (ml >= 0) ? ml : (SS - 1);
    }
}

// rowmean over H of write_weights; one wave per row
__global__ __launch_bounds__(256) void rowmean_kernel(
    const float* __restrict__ ww, float* __restrict__ rm)
{
    const int wv = threadIdx.x >> 6, lane = threadIdx.x & 63;
    const int row = blockIdx.x * 4 + wv;
    const float* p = ww + (size_t)row * HH + lane * 8;
    const float4 v0 = *(const float4*)p;
    const float4 v1 = *(const float4*)(p + 4);
    float s = v0.x + v0.y + v0.z + v0.w + v1.x + v1.y + v1.z + v1.w;
#pragma unroll
    for (int m = 1; m < 64; m <<= 1) s += __shfl_xor(s, m);
    if (lane == 0) rm[row] = s * (1.0f / (float)HH);
}

// per batch: first-occurrence argmax over M rowmeans
__global__ __launch_bounds__(256) void argmax_kernel(
    const float* __restrict__ rm, int* __restrict__ pos)
{
    const int b = blockIdx.x, tid = threadIdx.x;
    float best = -3.0e38f; int bidx = 1 << 30;
    for (int m = tid; m < MM; m += 256) {
        const float v = rm[b * MM + m];
        if (v > best || (v == best && m < bidx)) { best = v; bidx = m; }
    }
#pragma unroll
    for (int msk = 1; msk < 64; msk <<= 1) {
        const float ov = __shfl_xor(best, msk);
        const int oi = __shfl_xor(bidx, msk);
        if (ov > best || (ov == best && oi < bidx)) { best = ov; bidx = oi; }
    }
    __shared__ float sv[4]; __shared__ int si[4];
    if ((tid & 63) == 0) { sv[tid >> 6] = best; si[tid >> 6] = bidx; }
    __syncthreads();
    if (tid == 0) {
        for (int w = 1; w < 4; ++w)
            if (sv[w] > best || (sv[w] == best && si[w] < bidx)) { best = sv[w]; bidx = si[w]; }
        pos[b] = bidx;
    }
}

// per batch: upd = tanh(relu([old,sel]@Wu1+bu1)@Wu2+bu2); write updated row
__global__ __launch_bounds__(256) void update_kernel(
    const float* __restrict__ mb, const float* __restrict__ ni,
    const float* __restrict__ Wu1, const float* __restrict__ bu1,
    const float* __restrict__ Wu2, const float* __restrict__ bu2,
    const float* __restrict__ wwp, const int* __restrict__ pos,
    const int* __restrict__ s_star, const int* __restrict__ exists,
    float* __restrict__ outu)
{
    const int b = blockIdx.x, tid = threadIdx.x;
    __shared__ float comb[2 * DD];
    __shared__ float hu[HH];
    const int p = pos[b], ss = s_star[b], ex = exists[b];
    const float* oldp = mb + ((size_t)(b * MM + p)) * DD;
    const float* selp = ni + ((size_t)(b * SS + ss)) * DD;
    for (int i = tid; i < DD; i += 256) { comb[i] = oldp[i]; comb[DD + i] = selp[i]; }
    __syncthreads();
#pragma unroll
    for (int t = 0; t < 2; ++t) {
        const int n = tid + t * 256;
        float a = bu1[n];
        for (int k = 0; k < 2 * DD; ++k) a = fmaf(comb[k], Wu1[(size_t)k * HH + n], a);
        hu[n] = fmaxf(a, 0.f);
    }
    __syncthreads();
#pragma unroll
    for (int t = 0; t < 2; ++t) {
        const int n = tid + t * 256;
        float a = bu2[n];
        for (int k = 0; k < HH; ++k) a = fmaf(hu[k], Wu2[(size_t)k * HH + n], a);
        const float upd = tanhf(a);
        const float wwv = wwp[((size_t)(b * MM + p)) * HH + n];
        const float ov = oldp[n];
        outu[((size_t)(b * MM + p)) * DD + n] = ex ? fmaf(upd, wwv, ov) : ov;
    }
}

extern "C" void kernel_launch(void* const* d_in, const int* in_sizes, int n_in,
                              void* d_out, int out_size, void* d_ws, size_t ws_size,
                              hipStream_t stream)
{
    const float* new_info    = (const float*)d_in[0];
    const float* memory_bank = (const float*)d_in[1];
    const float* W_in = (const float*)d_in[2];  const float* b_in = (const float*)d_in[3];
    const float* Wq   = (const float*)d_in[4];  const float* bq   = (const float*)d_in[5];
    const float* Wk   = (const float*)d_in[6];  const float* bk   = (const float*)d_in[7];
    const float* Wv   = (const float*)d_in[8];  const float* bv   = (const float*)d_in[9];
    const float* Wo   = (const float*)d_in[10]; const float* bo   = (const float*)d_in[11];
    const float* Wi1  = (const float*)d_in[12]; const float* bi1  = (const float*)d_in[13];
    const float* Wi2  = (const float*)d_in[14]; const float* bi2  = (const float*)d_in[15];
    const float* Wu1  = (const float*)d_in[16]; const float* bu1  = (const float*)d_in[17];
    const float* Wu2  = (const float*)d_in[18]; const float* bu2  = (const float*)d_in[19];

    float* out = (float*)d_out;
    float* out_updated = out;                               // B*M*D
    float* out_ww      = out + (size_t)BB * MM * HH;        // B*M*H
    float* out_imp     = out + 2 * (size_t)BB * MM * HH;    // B*S

    // workspace layout (f32 units), ~141 MB
    float* ws = (float*)d_ws;
    float* info_proj = ws;                                  // 4,194,304
    float* qhb       = info_proj + 4194304;                 // 8,388,608 (hidden1 aliases)
    float* ip_sp     = qhb + 8388608;                       // 4,194,304 (iph/ipl)
    float* mb_sp     = ip_sp + 4194304;                     // 8,388,608 (mbh/mbl; attn out reuses)
    float* kvreg     = mb_sp + 8388608;                     // 8,388,608 (K/V splits)
    float* winq      = kvreg + 8388608;                     // 262,144
    float* wtf       = winq + 262144;                       // 1,310,720 (us pairs)
    float* bq_eff    = wtf + 1310720;                       // 512
    float* bkv       = bq_eff + 512;                        // 1024
    float* rowmeanv  = bkv + 1024;                          // 16,384
    float* imp_mean  = rowmeanv + 16384;                    // 8
    int*   ipos      = (int*)(imp_mean + BB);
    int*   istar     = ipos + BB;
    int*   iexists   = istar + BB;

    float* hidden1 = qhb;  // B*S*256, dead before Q-GEMM writes qhb

    us* iph = (us*)ip_sp;          // [8192][512]
    us* ipl = iph + 4194304;
    us* mbh = (us*)mb_sp;          // [16384][512]
    us* mbl = mbh + 8388608;
    us* Kh  = (us*)kvreg;          // [8192][512]
    us* Kl  = Kh + 4194304;
    us* Vth = Kl + 4194304;        // [8][512][1024]
    us* Vtl = Vth + 4194304;

    us* wtq_h   = (us*)wtf;            us* wtq_l   = wtq_h + 262144;
    us* wtkv_h  = wtq_l + 262144;      us* wtkv_l  = wtkv_h + 524288;   // [1024][512]
    us* wto_h   = wtkv_l + 524288;     us* wto_l   = wto_h + 262144;
    us* wtinq_h = wto_l + 262144;      us* wtinq_l = wtinq_h + 262144;

    const dim3 blk(256);

    // updated := memory_bank copy + bf16 hi/lo split (Q-GEMM A operand)
    copy_split<<<dim3(2048), blk, 0, stream>>>(memory_bank, out_updated,
                                               mbh, mbl, 1048576);

    // ---- weight prep: Wq, Wk|Wv (concat rows), Wo transposed+split
    TSB ts;
    ts.src[0] = Wq; ts.dh[0] = wtq_h;           ts.dl[0] = wtq_l;
    ts.src[1] = Wk; ts.dh[1] = wtkv_h;          ts.dl[1] = wtkv_l;
    ts.src[2] = Wv; ts.dh[2] = wtkv_h + 262144; ts.dl[2] = wtkv_l + 262144;
    ts.src[3] = Wo; ts.dh[3] = wto_h;           ts.dl[3] = wto_l;
    transpose_split_batch<<<dim3(16, 16, 4), blk, 0, stream>>>(ts);
    concat_bias<<<dim3(4), blk, 0, stream>>>(bk, bv, bkv);
    bias_fuse<<<dim3(2), blk, 0, stream>>>(b_in, Wq, bq, bq_eff);

    // ---- importance path stays exact f32; epilogue also emits split for KV
    gemm128<<<dim3(4, 64), blk, 0, stream>>>(new_info, W_in, b_in, info_proj,
                                             DD, HH, 0, iph, ipl);
    gemm128<<<dim3(2, 64), blk, 0, stream>>>(info_proj, Wi1, bi1, hidden1,
                                             HH, HH / 2, 1, nullptr, nullptr);
    imp_kernel<<<dim3((BB * SS) / 4), blk, 0, stream>>>(hidden1, Wi2, bi2, out_imp);
    impstats_kernel<<<dim3(BB), blk, 0, stream>>>(out_imp, imp_mean, istar, iexists);

    // ---- fused Q path: winq = W_in@Wq; Q = memory_bank@winq + bq_eff
    gemm_mfma<<<dim3(4, 4), blk, 0, stream>>>(W_in, wtq_h, wtq_l,
                                              nullptr, winq, 512, 512);
    TSB ts2;
    ts2.src[0] = winq; ts2.dh[0] = wtinq_h; ts2.dl[0] = wtinq_l;
    transpose_split_batch<<<dim3(16, 16, 1), blk, 0, stream>>>(ts2);
    gemm_mfma_ps<<<dim3(4, 128), blk, 0, stream>>>(mbh, mbl, 512,
                                                   wtinq_h, wtinq_l,
                                                   bq_eff, qhb, 512, 512, nullptr, 1);

    // ---- fused K|V GEMM -> pre-split K (row-major) + V (transposed)
    gemm_mfma_kv_ps<<<dim3(8, 64), blk, 0, stream>>>(iph, ipl, 512,
                                                     wtkv_h, wtkv_l, bkv,
                                                     Kh, Kl, Vth, Vtl, 512);

    // ---- MFMA flash attention -> pre-split output into mbh/mbl (dead now)
    attn_mfma<<<dim3(2048), blk, 0, stream>>>(qhb, Kh, Kl, Vth, Vtl, mbh, mbl);

    // ---- output projection (+ imp_mean rowscale) -> write_weights
    gemm_mfma_ps<<<dim3(4, 128), blk, 0, stream>>>(mbh, mbl, 512,
                                                   wto_h, wto_l,
                                                   bo, out_ww, 512, 512, imp_mean, MM);

    // ---- slot selection + final row update
    rowmean_kernel<<<dim3((BB * MM) / 4), blk, 0, stream>>>(out_ww, rowmeanv);
    argmax_kernel<<<dim3(BB), blk, 0, stream>>>(rowmeanv, ipos);
    update_kernel<<<dim3(BB), blk, 0, stream>>>(memory_bank, new_info,
                                                Wu1, bu1, Wu2, bu2, out_ww,
                                                ipos, istar, iexists, out_updated);
}

// Round 11
// 562.168 us; speedup vs baseline: 1.0750x; 1.0750x over previous
//
#include <hip/hip_runtime.h>
#include <hip/hip_bf16.h>
#include <math.h>

// Problem constants (AttentionWriter): B=8,S=1024,M=2048,D=512,H=512,NH=8,Dh=64
#define BB 8
#define SS 1024
#define MM 2048
#define DD 512
#define HH 512
#define NHEAD 8
#define DHEAD 64

typedef __attribute__((ext_vector_type(8))) short short8;
typedef __attribute__((ext_vector_type(4))) float f32x4;
typedef unsigned short us;

// bf16 split helpers — native cvt (v_cvt_pk_bf16_f32), RNE, ~4x fewer VALU
__device__ __forceinline__ us bf_hi(float x) {
    __hip_bfloat16 h = __float2bfloat16(x);
    return *reinterpret_cast<const us*>(&h);
}
__device__ __forceinline__ float bf_f(us h) {
    return __uint_as_float(((unsigned)h) << 16);
}
__device__ __forceinline__ void split_pack4(float a, float b, float c, float d,
                                            uint2& hp, uint2& lp) {
    us h0 = bf_hi(a), h1 = bf_hi(b), h2 = bf_hi(c), h3 = bf_hi(d);
    hp.x = (unsigned)h0 | ((unsigned)h1 << 16);
    hp.y = (unsigned)h2 | ((unsigned)h3 << 16);
    us l0 = bf_hi(a - bf_f(h0)), l1 = bf_hi(b - bf_f(h1));
    us l2 = bf_hi(c - bf_f(h2)), l3 = bf_hi(d - bf_f(h3));
    lp.x = (unsigned)l0 | ((unsigned)l1 << 16);
    lp.y = (unsigned)l2 | ((unsigned)l3 << 16);
}

// async global->LDS DMA, 16B per lane; LDS dest = wave-uniform base + lane*16
__device__ __forceinline__ void gload_lds16(const void* g, void* l) {
    __builtin_amdgcn_global_load_lds(
        (__attribute__((address_space(1))) void*)(g),
        (__attribute__((address_space(3))) void*)(l), 16, 0, 0);
}

// ---------------------------------------------------------------------------
// copy memory_bank -> out_updated + bf16 hi/lo split; tail blocks zero rowmeanv
// ---------------------------------------------------------------------------
__global__ __launch_bounds__(256) void copy_split(
    const float* __restrict__ x, float* __restrict__ cpy,
    us* __restrict__ hi, us* __restrict__ lo, int n8, float* __restrict__ zbuf)
{
    if (blockIdx.x >= 2048) {   // zero rowmeanv (16384 floats, 8 blocks)
        const int i = (blockIdx.x - 2048) * 2048 + threadIdx.x * 8;
        *(float4*)(zbuf + i) = make_float4(0.f, 0.f, 0.f, 0.f);
        *(float4*)(zbuf + i + 4) = make_float4(0.f, 0.f, 0.f, 0.f);
        return;
    }
    const int stride = 2048 * 256;
    for (int i = blockIdx.x * 256 + threadIdx.x; i < n8; i += stride) {
        const float4 a = *(const float4*)(x + (size_t)i * 8);
        const float4 b = *(const float4*)(x + (size_t)i * 8 + 4);
        *(float4*)(cpy + (size_t)i * 8) = a;
        *(float4*)(cpy + (size_t)i * 8 + 4) = b;
        uint2 h0, l0, h1, l1;
        split_pack4(a.x, a.y, a.z, a.w, h0, l0);
        split_pack4(b.x, b.y, b.z, b.w, h1, l1);
        *(uint2*)(hi + (size_t)i * 8) = h0;
        *(uint2*)(hi + (size_t)i * 8 + 4) = h1;
        *(uint2*)(lo + (size_t)i * 8) = l0;
        *(uint2*)(lo + (size_t)i * 8 + 4) = l1;
    }
}

// ---------------------------------------------------------------------------
// f32 GEMM (precision-sensitive importance path ONLY); optional split-out
// ---------------------------------------------------------------------------
__global__ __launch_bounds__(256) void gemm128(
    const float* __restrict__ A, const float* __restrict__ W,
    const float* __restrict__ bias, float* __restrict__ C,
    int K, int N, int act, us* __restrict__ hi_out, us* __restrict__ lo_out)
{
    __shared__ float As[8][132];
    __shared__ float Bs[8][128];
    const int tid  = threadIdx.x;
    const int row0 = blockIdx.y * 128, col0 = blockIdx.x * 128;
    const int ty = tid >> 4, tx = tid & 15;

    const int arow = tid >> 1,  ak4  = (tid & 1) * 4;
    const int bk   = tid >> 5,  bcol = (tid & 31) * 4;

    const float* Ap = A + (size_t)(row0 + arow) * K + ak4;
    const float* Wp = W + (size_t)bk * N + col0 + bcol;

    float4 aReg = *(const float4*)Ap;
    float4 bReg = *(const float4*)Wp;

    float acc[8][8];
#pragma unroll
    for (int i = 0; i < 8; ++i)
#pragma unroll
        for (int j = 0; j < 8; ++j) acc[i][j] = 0.f;

    for (int k0 = 0; k0 < K; k0 += 8) {
        __syncthreads();
        As[ak4 + 0][arow] = aReg.x;
        As[ak4 + 1][arow] = aReg.y;
        As[ak4 + 2][arow] = aReg.z;
        As[ak4 + 3][arow] = aReg.w;
        *(float4*)&Bs[bk][bcol] = bReg;
        __syncthreads();
        if (k0 + 8 < K) {
            aReg = *(const float4*)(Ap + k0 + 8);
            bReg = *(const float4*)(Wp + (size_t)(k0 + 8) * N);
        }
#pragma unroll
        for (int kk = 0; kk < 8; ++kk) {
            float a[8], b[8];
            *(float4*)&a[0] = *(const float4*)&As[kk][ty * 8];
            *(float4*)&a[4] = *(const float4*)&As[kk][ty * 8 + 4];
            *(float4*)&b[0] = *(const float4*)&Bs[kk][tx * 4];
            *(float4*)&b[4] = *(const float4*)&Bs[kk][64 + tx * 4];
#pragma unroll
            for (int i = 0; i < 8; ++i)
#pragma unroll
                for (int j = 0; j < 8; ++j)
                    acc[i][j] = fmaf(a[i], b[j], acc[i][j]);
        }
    }

#pragma unroll
    for (int i = 0; i < 8; ++i) {
        const int r = row0 + ty * 8 + i;
#pragma unroll
        for (int half = 0; half < 2; ++half) {
            const int c = col0 + half * 64 + tx * 4;
            float4 bv = bias ? *(const float4*)&bias[c] : make_float4(0.f, 0.f, 0.f, 0.f);
            float4 v;
            v.x = acc[i][half * 4 + 0] + bv.x;
            v.y = acc[i][half * 4 + 1] + bv.y;
            v.z = acc[i][half * 4 + 2] + bv.z;
            v.w = acc[i][half * 4 + 3] + bv.w;
            if (act == 1) {
                v.x = fmaxf(v.x, 0.f); v.y = fmaxf(v.y, 0.f);
                v.z = fmaxf(v.z, 0.f); v.w = fmaxf(v.w, 0.f);
            }
            *(float4*)&C[(size_t)r * N + c] = v;
            if (hi_out) {
                uint2 hp, lp;
                split_pack4(v.x, v.y, v.z, v.w, hp, lp);
                *(uint2*)&hi_out[(size_t)r * N + c] = hp;
                *(uint2*)&lo_out[(size_t)r * N + c] = lp;
            }
        }
    }
}

// ---------------------------------------------------------------------------
// batched transpose+split of [512][512] f32 weights -> [n][k] bf16 hi/lo
// ---------------------------------------------------------------------------
struct TSB {
    const float* src[6];
    us* dh[6];
    us* dl[6];
};
__global__ __launch_bounds__(256) void transpose_split_batch(TSB a)
{
    __shared__ float tile[32][33];
    const int tid = threadIdx.x;
    const int n0 = blockIdx.x * 32, k0 = blockIdx.y * 32;
    const int wsel = blockIdx.z;
    const float* W = a.src[wsel];
    {
        const int r = tid >> 3, c = (tid & 7) * 4;
        const float4 v = *(const float4*)(W + (size_t)(k0 + r) * 512 + n0 + c);
        tile[r][c + 0] = v.x; tile[r][c + 1] = v.y;
        tile[r][c + 2] = v.z; tile[r][c + 3] = v.w;
    }
    __syncthreads();
    {
        const int n = tid >> 3, k = (tid & 7) * 4;
        uint2 hp, lp;
        split_pack4(tile[k + 0][n], tile[k + 1][n], tile[k + 2][n], tile[k + 3][n], hp, lp);
        *(uint2*)(a.dh[wsel] + (size_t)(n0 + n) * 512 + k0 + k) = hp;
        *(uint2*)(a.dl[wsel] + (size_t)(n0 + n) * 512 + k0 + k) = lp;
    }
}

// merged: blocks 0-3 concat bk|bv -> bkv; blocks 4-5 bias_fuse bq_eff
__global__ __launch_bounds__(256) void bias_prep(
    const float* __restrict__ bk, const float* __restrict__ bv,
    float* __restrict__ bkv,
    const float* __restrict__ b_in, const float* __restrict__ Wq,
    const float* __restrict__ bq, float* __restrict__ bq_eff)
{
    const int blk = blockIdx.x, tid = threadIdx.x;
    if (blk < 4) {
        const int i = blk * 256 + tid;
        bkv[i] = (i < 512) ? bk[i] : bv[i - 512];
    } else {
        const int n = (blk - 4) * 256 + tid;
        float a = bq[n];
        for (int k = 0; k < 512; ++k) a = fmaf(b_in[k], Wq[(size_t)k * 512 + n], a);
        bq_eff[n] = a;
    }
}

// ---------------------------------------------------------------------------
// OLD split-bf16 MFMA GEMM (f32 A split in-kernel) — kept ONLY for tiny winq
// ---------------------------------------------------------------------------
__global__ __launch_bounds__(256) void gemm_mfma(
    const float* __restrict__ A,
    const us* __restrict__ Bh, const us* __restrict__ Bl,
    const float* __restrict__ bias, float* __restrict__ C, int K, int N)
{
    __shared__ us sm[32768];
    us* sAh = sm;            us* sAl = sm + 8192;
    us* sBh = sm + 16384;    us* sBl = sm + 24576;
    const int tid = threadIdx.x, lane = tid & 63;
    const int wid = tid >> 6, wm = wid >> 1, wn = wid & 1;
    const int m0 = blockIdx.y * 128, n0 = blockIdx.x * 128;
    const int fr = lane & 15, fq4 = lane >> 4;
    f32x4 acc[4][4];
#pragma unroll
    for (int i = 0; i < 4; ++i)
#pragma unroll
        for (int j = 0; j < 4; ++j)
#pragma unroll
            for (int r = 0; r < 4; ++r) acc[i][j][r] = 0.f;
    const int ar = tid >> 4;
    const int ak = (tid & 15) * 4;
    int bsrow[4], bsf[4], bsoff[4];
#pragma unroll
    for (int it = 0; it < 4; ++it) {
        const int s = tid + 256 * it;
        bsrow[it] = s >> 3;
        bsf[it] = s & 7;
        bsoff[it] = bsrow[it] * 64 + ((bsf[it] ^ (bsrow[it] & 7)) << 3);
    }
    for (int k0 = 0; k0 < K; k0 += 64) {
        __syncthreads();
#pragma unroll
        for (int p = 0; p < 8; ++p) {
            const int r = p * 16 + ar;
            const float4 av = *(const float4*)(A + (size_t)(m0 + r) * K + k0 + ak);
            const int aoff = r * 128 + (((ak >> 3) ^ (r & 7)) << 4) + ((tid & 1) << 3);
            uint2 hp, lp;
            split_pack4(av.x, av.y, av.z, av.w, hp, lp);
            *(uint2*)((char*)sAh + aoff) = hp;
            *(uint2*)((char*)sAl + aoff) = lp;
        }
#pragma unroll
        for (int it = 0; it < 4; ++it) {
            const size_t bo = (size_t)(n0 + bsrow[it]) * K + k0 + bsf[it] * 8;
            *(uint4*)(sBh + bsoff[it]) = *(const uint4*)(Bh + bo);
            *(uint4*)(sBl + bsoff[it]) = *(const uint4*)(Bl + bo);
        }
        __syncthreads();
#pragma unroll
        for (int ks = 0; ks < 2; ++ks) {
            short8 afh[4], afl[4], bfh[4], bfl[4];
#pragma unroll
            for (int i = 0; i < 4; ++i) {
                const int row = wm * 64 + i * 16 + fr;
                const int off = row * 128 + (((ks * 4 + fq4) ^ (row & 7)) << 4);
                afh[i] = *(const short8*)((const char*)sAh + off);
                afl[i] = *(const short8*)((const char*)sAl + off);
            }
#pragma unroll
            for (int j = 0; j < 4; ++j) {
                const int row = wn * 64 + j * 16 + fr;
                const int off = row * 128 + (((ks * 4 + fq4) ^ (row & 7)) << 4);
                bfh[j] = *(const short8*)((const char*)sBh + off);
                bfl[j] = *(const short8*)((const char*)sBl + off);
            }
#pragma unroll
            for (int i = 0; i < 4; ++i)
#pragma unroll
                for (int j = 0; j < 4; ++j) {
                    acc[i][j] = __builtin_amdgcn_mfma_f32_16x16x32_bf16(afh[i], bfh[j], acc[i][j], 0, 0, 0);
                    acc[i][j] = __builtin_amdgcn_mfma_f32_16x16x32_bf16(afh[i], bfl[j], acc[i][j], 0, 0, 0);
                    acc[i][j] = __builtin_amdgcn_mfma_f32_16x16x32_bf16(afl[i], bfh[j], acc[i][j], 0, 0, 0);
                }
        }
    }
#pragma unroll
    for (int j = 0; j < 4; ++j) {
        const int col = n0 + wn * 64 + j * 16 + fr;
        const float bj = bias ? bias[col] : 0.f;
#pragma unroll
        for (int i = 0; i < 4; ++i)
#pragma unroll
            for (int r = 0; r < 4; ++r) {
                const int row = m0 + wm * 64 + i * 16 + fq4 * 4 + r;
                C[(size_t)row * N + col] = acc[i][j][r] + bj;
            }
    }
}

// ---------------------------------------------------------------------------
// PRE-SPLIT MFMA GEMM core: expects sm,tid,lane,wid,wm,wn,fr,fq4,m0,n0 in
// scope; stages Ah|Al|Bh|Bl via global_load_lds (wave wid stages array wid),
// XOR frag swizzle pre-applied on global source addr. Produces acc[4][4].
// ---------------------------------------------------------------------------
#define GEMM_PS_CORE(AhP, AlP, BhP, BlP, rsA_, K_)                                  \
    us* sAh = sm;            us* sAl = sm + 8192;                                   \
    us* sBh = sm + 16384;    us* sBl = sm + 24576;                                  \
    f32x4 acc[4][4];                                                                \
    _Pragma("unroll")                                                               \
    for (int i = 0; i < 4; ++i)                                                     \
        _Pragma("unroll")                                                           \
        for (int j = 0; j < 4; ++j)                                                 \
            _Pragma("unroll")                                                       \
            for (int r = 0; r < 4; ++r) acc[i][j][r] = 0.f;                         \
    const int fp = lane & 7, rsub = lane >> 3;                                      \
    const us* gsrc = (wid == 0) ? (AhP) : (wid == 1) ? (AlP)                        \
                   : (wid == 2) ? (BhP) : (BlP);                                    \
    const int grow0 = (wid < 2) ? m0 : n0;                                          \
    const int grs = (wid < 2) ? (rsA_) : (K_);                                      \
    us* lbase = sm + wid * 8192;                                                    \
    for (int k0 = 0; k0 < (K_); k0 += 64) {                                         \
        __syncthreads();                                                            \
        _Pragma("unroll")                                                           \
        for (int i = 0; i < 16; ++i) {                                              \
            const int row = i * 8 + rsub;                                           \
            const us* g = gsrc + (size_t)(grow0 + row) * grs + k0 +                 \
                          ((fp ^ (row & 7)) << 3);                                  \
            gload_lds16(g, lbase + i * 512);                                        \
        }                                                                           \
        __syncthreads();                                                            \
        _Pragma("unroll")                                                           \
        for (int ks = 0; ks < 2; ++ks) {                                            \
            short8 afh[4], afl[4], bfh[4], bfl[4];                                  \
            _Pragma("unroll")                                                       \
            for (int i = 0; i < 4; ++i) {                                           \
                const int row = wm * 64 + i * 16 + fr;                              \
                const int off = row * 128 + (((ks * 4 + fq4) ^ (row & 7)) << 4);    \
                afh[i] = *(const short8*)((const char*)sAh + off);                  \
                afl[i] = *(const short8*)((const char*)sAl + off);                  \
            }                                                                       \
            _Pragma("unroll")                                                       \
            for (int j = 0; j < 4; ++j) {                                           \
                const int row = wn * 64 + j * 16 + fr;                              \
                const int off = row * 128 + (((ks * 4 + fq4) ^ (row & 7)) << 4);    \
                bfh[j] = *(const short8*)((const char*)sBh + off);                  \
                bfl[j] = *(const short8*)((const char*)sBl + off);                  \
            }                                                                       \
            _Pragma("unroll")                                                       \
            for (int i = 0; i < 4; ++i)                                             \
                _Pragma("unroll")                                                   \
                for (int j = 0; j < 4; ++j) {                                       \
                    acc[i][j] = __builtin_amdgcn_mfma_f32_16x16x32_bf16(afh[i], bfh[j], acc[i][j], 0, 0, 0); \
                    acc[i][j] = __builtin_amdgcn_mfma_f32_16x16x32_bf16(afh[i], bfl[j], acc[i][j], 0, 0, 0); \
                    acc[i][j] = __builtin_amdgcn_mfma_f32_16x16x32_bf16(afl[i], bfh[j], acc[i][j], 0, 0, 0); \
                }                                                                   \
        }                                                                           \
    }

// ---------------------------------------------------------------------------
// merged Q-GEMM + KV-GEMM: 1024 blocks, id<512 -> Q tile, else KV tile.
// Q: qhb = mbh/mbl @ wtinq^T + bq_eff  (M=16384,N=512)
// KV: iph/ipl @ wtkv^T + bkv -> K rows pre-split / V transposed pre-split
// ---------------------------------------------------------------------------
__global__ __launch_bounds__(256) void gemm_qkv_ps(
    const us* __restrict__ mbh, const us* __restrict__ mbl,
    const us* __restrict__ wtinq_h, const us* __restrict__ wtinq_l,
    const float* __restrict__ bq_eff, float* __restrict__ qout,
    const us* __restrict__ iph, const us* __restrict__ ipl,
    const us* __restrict__ wtkv_h, const us* __restrict__ wtkv_l,
    const float* __restrict__ bkv,
    us* __restrict__ Kh, us* __restrict__ Kl,
    us* __restrict__ Vth, us* __restrict__ Vtl)
{
    __shared__ us sm[32768];
    const int tid = threadIdx.x, lane = tid & 63;
    const int wid = tid >> 6, wm = wid >> 1, wn = wid & 1;
    const int fr = lane & 15, fq4 = lane >> 4;
    const int id = blockIdx.x;
    const bool isQ = (id < 512);
    int m0, n0;
    const us *Ah, *Al, *Bh, *Bl;
    if (isQ) {
        m0 = (id >> 2) * 128; n0 = (id & 3) * 128;
        Ah = mbh; Al = mbl; Bh = wtinq_h; Bl = wtinq_l;
    } else {
        const int t = id - 512;
        m0 = (t >> 3) * 128; n0 = (t & 7) * 128;
        Ah = iph; Al = ipl; Bh = wtkv_h; Bl = wtkv_l;
    }
    GEMM_PS_CORE(Ah, Al, Bh, Bl, 512, 512)

    if (isQ) {
#pragma unroll
        for (int j = 0; j < 4; ++j) {
            const int col = n0 + wn * 64 + j * 16 + fr;
            const float bj = bq_eff[col];
#pragma unroll
            for (int i = 0; i < 4; ++i)
#pragma unroll
                for (int r = 0; r < 4; ++r) {
                    const int row = m0 + wm * 64 + i * 16 + fq4 * 4 + r;
                    qout[(size_t)row * 512 + col] = acc[i][j][r] + bj;
                }
        }
    } else if (n0 < 512) {
#pragma unroll
        for (int j = 0; j < 4; ++j) {
            const int col = n0 + wn * 64 + j * 16 + fr;
            const float bj = bkv[col];
#pragma unroll
            for (int i = 0; i < 4; ++i)
#pragma unroll
                for (int r = 0; r < 4; ++r) {
                    const int row = m0 + wm * 64 + i * 16 + fq4 * 4 + r;
                    const float v = acc[i][j][r] + bj;
                    const us hv = bf_hi(v);
                    Kh[(size_t)row * 512 + col] = hv;
                    Kl[(size_t)row * 512 + col] = bf_hi(v - bf_f(hv));
                }
        }
    } else {
#pragma unroll
        for (int j = 0; j < 4; ++j) {
            const int col = n0 + wn * 64 + j * 16 + fr;
            const float bj = bkv[col];
            const int d = col - 512;
#pragma unroll
            for (int i = 0; i < 4; ++i) {
                const int row0 = m0 + wm * 64 + i * 16 + fq4 * 4;
                uint2 hp, lp;
                split_pack4(acc[i][j][0] + bj, acc[i][j][1] + bj,
                            acc[i][j][2] + bj, acc[i][j][3] + bj, hp, lp);
                const size_t vo = ((size_t)(row0 >> 10) * 512 + d) * 1024 + (row0 & 1023);
                *(uint2*)(Vth + vo) = hp;
                *(uint2*)(Vtl + vo) = lp;
            }
        }
    }
}

// ---------------------------------------------------------------------------
// Wo-GEMM with fused rowmean: ww = (aoh/aol @ wto^T + bo) * imp_mean[row/M];
// per-block LDS row-partials -> one global atomicAdd per row per block.
// ---------------------------------------------------------------------------
__global__ __launch_bounds__(256) void gemm_wo_ps(
    const us* __restrict__ Ah, const us* __restrict__ Al,
    const us* __restrict__ Bh, const us* __restrict__ Bl,
    const float* __restrict__ bias, float* __restrict__ C,
    const float* __restrict__ rowscale, float* __restrict__ rowmeanv)
{
    __shared__ us sm[32768];
    const int tid = threadIdx.x, lane = tid & 63;
    const int wid = tid >> 6, wm = wid >> 1, wn = wid & 1;
    const int fr = lane & 15, fq4 = lane >> 4;
    const int m0 = blockIdx.y * 128, n0 = blockIdx.x * 128;
    GEMM_PS_CORE(Ah, Al, Bh, Bl, 512, 512)

    float rsum[4][4];
#pragma unroll
    for (int i = 0; i < 4; ++i)
#pragma unroll
        for (int r = 0; r < 4; ++r) rsum[i][r] = 0.f;

#pragma unroll
    for (int j = 0; j < 4; ++j) {
        const int col = n0 + wn * 64 + j * 16 + fr;
        const float bj = bias[col];
#pragma unroll
        for (int i = 0; i < 4; ++i)
#pragma unroll
            for (int r = 0; r < 4; ++r) {
                const int row = m0 + wm * 64 + i * 16 + fq4 * 4 + r;
                const float v = (acc[i][j][r] + bj) * rowscale[row / MM];
                C[(size_t)row * 512 + col] = v;
                rsum[i][r] += v;
            }
    }

    __syncthreads();                       // staging LDS reads done -> reuse
    float* red = (float*)sm;               // 128 row-partials
    if (tid < 128) red[tid] = 0.f;
    __syncthreads();
#pragma unroll
    for (int i = 0; i < 4; ++i)
#pragma unroll
        for (int r = 0; r < 4; ++r)
            atomicAdd(&red[wm * 64 + i * 16 + fq4 * 4 + r], rsum[i][r]);
    __syncthreads();
    if (tid < 128) atomicAdd(&rowmeanv[m0 + tid], red[tid] * (1.0f / 512.0f));
}

// ---------------------------------------------------------------------------
// MFMA flash attention (R9 structure, faster split): DMA-staged K/V,
// spill-free; epilogue emits pre-split hi/lo into mbh/mbl (dead after Q-GEMM).
// ---------------------------------------------------------------------------
__global__ __launch_bounds__(256) void attn_mfma(
    const float* __restrict__ qh,
    const us* __restrict__ Kh, const us* __restrict__ Kl,
    const us* __restrict__ Vth, const us* __restrict__ Vtl,
    us* __restrict__ aoh, us* __restrict__ aol)
{
    __shared__ us sm[24576];    // sKh|sKl|sVh|sVl (4096 us each) | sPh|sPl
    __shared__ float sSc[64];
    us* sKh = sm;            us* sKl = sm + 4096;
    us* sVh = sm + 8192;     us* sVl = sm + 12288;
    us* sPh = sm + 16384;    us* sPl = sm + 20480;

    const int tid = threadIdx.x, lane = tid & 63, w = tid >> 6;
    const int fr = lane & 15, fq4 = lane >> 4;

    // XCD swizzle: 32 blocks sharing one (b,h) K/V slice land on one XCD
    const int wg = blockIdx.x;              // 0..2047
    const int xcd = wg & 7, ix = wg >> 3;   // ix 0..255
    const int mt = ix & 31;
    const int pair = xcd + 8 * (ix >> 5);   // 0..63
    const int h = pair & 7, b = pair >> 3;
    const int m0 = mt * 64;

    const float* Qg = qh + ((size_t)(b * MM + m0)) * HH + h * DHEAD;
    const us* Kgh = Kh + ((size_t)b * SS) * 512 + h * DHEAD;
    const us* Kgl = Kl + ((size_t)b * SS) * 512 + h * DHEAD;
    const us* Vgh = Vth + ((size_t)b * 512 + h * DHEAD) * 1024;
    const us* Vgl = Vtl + ((size_t)b * 512 + h * DHEAD) * 1024;
    us* Oh = aoh + ((size_t)(b * MM + m0)) * 512 + h * DHEAD;
    us* Ol = aol + ((size_t)(b * MM + m0)) * 512 + h * DHEAD;

    // ---- Q fragments in registers (pre-scaled by 1/8), hi/lo split
    short8 qfh[2], qfl[2];   // [ks]
#pragma unroll
    for (int ks = 0; ks < 2; ++ks) {
        const float* qp = Qg + (size_t)(w * 16 + fr) * HH + ks * 32 + fq4 * 8;
        const float4 u0 = *(const float4*)qp;
        const float4 u1 = *(const float4*)(qp + 4);
        float v[8] = {u0.x, u0.y, u0.z, u0.w, u1.x, u1.y, u1.z, u1.w};
#pragma unroll
        for (int e = 0; e < 8; ++e) {
            const float x = v[e] * 0.125f;
            const us hb = bf_hi(x);
            qfh[ks][e] = (short)hb;
            qfl[ks][e] = (short)bf_hi(x - bf_f(hb));
        }
    }

    // DMA staging: wave w stages array w; lane -> (row = i*8+lane>>3, fp=lane&7)
    const int fp = lane & 7;
    const int rsub = lane >> 3;
    const bool isK = (w < 2);
    const us* gA = (w == 0) ? Kgh : (w == 1) ? Kgl : (w == 2) ? Vgh : Vgl;
    us* lbase = sm + w * 4096;

    f32x4 oacc[4];
#pragma unroll
    for (int j = 0; j < 4; ++j)
#pragma unroll
        for (int r = 0; r < 4; ++r) oacc[j][r] = 0.f;
    float mrun = -1e30f, lrun = 0.f;

    for (int t = 0; t < SS / 64; ++t) {
        __syncthreads();                 // prev chunk's LDS reads done
        if (isK) {
#pragma unroll
            for (int i = 0; i < 8; ++i) {
                const int row = i * 8 + rsub;
                const us* g = gA + (size_t)(t * 64 + row) * 512 + ((fp ^ (row & 7)) << 3);
                gload_lds16(g, lbase + i * 512);
            }
        } else {
#pragma unroll
            for (int i = 0; i < 8; ++i) {
                const int row = i * 8 + rsub;   // row = d
                const us* g = gA + (size_t)row * 1024 + t * 64 + ((fp ^ (row & 7)) << 3);
                gload_lds16(g, lbase + i * 512);
            }
        }
        __syncthreads();                 // drains vmcnt -> staging visible

        // ---- QK^T (swapped): stt[fs] = K-slice x Q^T; C: row=s, col=q=fr
        f32x4 stt[4];
#pragma unroll
        for (int fs = 0; fs < 4; ++fs)
#pragma unroll
            for (int r = 0; r < 4; ++r) stt[fs][r] = 0.f;
#pragma unroll
        for (int ks = 0; ks < 2; ++ks) {
            short8 kfh[4], kfl[4];
#pragma unroll
            for (int fs = 0; fs < 4; ++fs) {
                const int row = fs * 16 + fr;
                const int off = row * 128 + (((ks * 4 + fq4) ^ (row & 7)) << 4);
                kfh[fs] = *(const short8*)((const char*)sKh + off);
                kfl[fs] = *(const short8*)((const char*)sKl + off);
            }
#pragma unroll
            for (int fs = 0; fs < 4; ++fs) {
                stt[fs] = __builtin_amdgcn_mfma_f32_16x16x32_bf16(kfh[fs], qfh[ks], stt[fs], 0, 0, 0);
                stt[fs] = __builtin_amdgcn_mfma_f32_16x16x32_bf16(kfh[fs], qfl[ks], stt[fs], 0, 0, 0);
                stt[fs] = __builtin_amdgcn_mfma_f32_16x16x32_bf16(kfl[fs], qfh[ks], stt[fs], 0, 0, 0);
            }
        }

        // ---- online softmax (q = fr; s spans 4 regs x 4 fs x 4 quarters)
        {
            float mx = stt[0][0];
#pragma unroll
            for (int fs = 0; fs < 4; ++fs)
#pragma unroll
                for (int r = 0; r < 4; ++r) mx = fmaxf(mx, stt[fs][r]);
            mx = fmaxf(mx, __shfl_xor(mx, 16));
            mx = fmaxf(mx, __shfl_xor(mx, 32));
            const float nm = fmaxf(mrun, mx);
            const float scf = __expf(mrun - nm);
            mrun = nm;
            float ps = 0.f;
#pragma unroll
            for (int fs = 0; fs < 4; ++fs)
#pragma unroll
                for (int r = 0; r < 4; ++r) {
                    const float p = __expf(stt[fs][r] - nm);
                    stt[fs][r] = p;
                    ps += p;
                }
            ps += __shfl_xor(ps, 16);
            ps += __shfl_xor(ps, 32);
            lrun = lrun * scf + ps;
            if (fq4 == 0) sSc[w * 16 + fr] = scf;
        }

        // ---- write P[q][s] hi/lo (wave-private rows, no barrier needed)
#pragma unroll
        for (int fs = 0; fs < 4; ++fs) {
            const int q = w * 16 + fr;
            const int flog = (fs << 1) | (fq4 >> 1);
            const int off = q * 128 + ((flog ^ (q & 7)) << 4) + ((fq4 & 1) << 3);
            uint2 hp, lp;
            split_pack4(stt[fs][0], stt[fs][1], stt[fs][2], stt[fs][3], hp, lp);
            *(uint2*)((char*)sPh + off) = hp;
            *(uint2*)((char*)sPl + off) = lp;
        }

        // ---- rescale oacc (q = w*16 + fq4*4 + r)
#pragma unroll
        for (int r = 0; r < 4; ++r) {
            const float scv = sSc[w * 16 + fq4 * 4 + r];
#pragma unroll
            for (int fd = 0; fd < 4; ++fd) oacc[fd][r] *= scv;
        }

        // ---- PV: oacc[fd] += P x V
#pragma unroll
        for (int ks = 0; ks < 2; ++ks) {
            short8 pfh, pfl, vfh[4], vfl[4];
            {
                const int row = w * 16 + fr;
                const int off = row * 128 + (((ks * 4 + fq4) ^ (row & 7)) << 4);
                pfh = *(const short8*)((const char*)sPh + off);
                pfl = *(const short8*)((const char*)sPl + off);
            }
#pragma unroll
            for (int fd = 0; fd < 4; ++fd) {
                const int row = fd * 16 + fr;
                const int off = row * 128 + (((ks * 4 + fq4) ^ (row & 7)) << 4);
                vfh[fd] = *(const short8*)((const char*)sVh + off);
                vfl[fd] = *(const short8*)((const char*)sVl + off);
            }
#pragma unroll
            for (int fd = 0; fd < 4; ++fd) {
                oacc[fd] = __builtin_amdgcn_mfma_f32_16x16x32_bf16(pfh, vfh[fd], oacc[fd], 0, 0, 0);
                oacc[fd] = __builtin_amdgcn_mfma_f32_16x16x32_bf16(pfh, vfl[fd], oacc[fd], 0, 0, 0);
                oacc[fd] = __builtin_amdgcn_mfma_f32_16x16x32_bf16(pfl, vfh[fd], oacc[fd], 0, 0, 0);
            }
        }
    }

    // ---- normalize + store PRE-SPLIT (hi/lo)
    if (fq4 == 0) sSc[w * 16 + fr] = lrun;
#pragma unroll
    for (int r = 0; r < 4; ++r) {
        const float inv = 1.0f / sSc[w * 16 + fq4 * 4 + r];
        const int q = w * 16 + fq4 * 4 + r;
#pragma unroll
        for (int fd = 0; fd < 4; ++fd) {
            const float v = oacc[fd][r] * inv;
            const us hv = bf_hi(v);
            Oh[(size_t)q * 512 + fd * 16 + fr] = hv;
            Ol[(size_t)q * 512 + fd * 16 + fr] = bf_hi(v - bf_f(hv));
        }
    }
}

// imp[row] = sigmoid(dot(h1[row,0:256], Wi2) + bi2); one wave per row
__global__ __launch_bounds__(256) void imp_kernel(
    const float* __restrict__ h1, const float* __restrict__ Wi2,
    const float* __restrict__ bi2, float* __restrict__ imp)
{
    const int wv = threadIdx.x >> 6, lane = threadIdx.x & 63;
    const int row = blockIdx.x * 4 + wv;
    const float4 hv = *(const float4*)(h1 + (size_t)row * 256 + lane * 4);
    const float4 wvv = *(const float4*)(Wi2 + lane * 4);
    float s = hv.x * wvv.x + hv.y * wvv.y + hv.z * wvv.z + hv.w * wvv.w;
#pragma unroll
    for (int m = 1; m < 64; m <<= 1) s += __shfl_xor(s, m);
    if (lane == 0) imp[row] = 1.0f / (1.0f + expf(-(s + bi2[0])));
}

// per batch: mean(imp), last index with imp>0.5, exists
__global__ __launch_bounds__(256) void impstats_kernel(
    const float* __restrict__ imp, float* __restrict__ imp_mean,
    int* __restrict__ s_star, int* __restrict__ exists)
{
    const int b = blockIdx.x, tid = threadIdx.x;
    float sum = 0.f; int last = -1;
    for (int s = tid; s < SS; s += 256) {
        const float v = imp[b * SS + s];
        sum += v;
        if (v > 0.5f) last = s;
    }
#pragma unroll
    for (int m = 1; m < 64; m <<= 1) {
        sum += __shfl_xor(sum, m);
        last = max(last, __shfl_xor(last, m));
    }
    __shared__ float ssum[4]; __shared__ int slast[4];
    if ((tid & 63) == 0) { ssum[tid >> 6] = sum; slast[tid >> 6] = last; }
    __syncthreads();
    if (tid == 0) {
        const float t = ssum[0] + ssum[1] + ssum[2] + ssum[3];
        const int ml = max(max(slast[0], slast[1]), max(slast[2], slast[3]));
        imp_mean[b] = t / (float)SS;
        exists[b] = (ml >= 0) ? 1 : 0;
        s_star[b] = (ml >= 0) ? ml : (SS - 1);
    }
}

// per batch: first-occurrence argmax over M rowmeans
__global__ __launch_bounds__(256) void argmax_kernel(
    const float* __restrict__ rm, int* __restrict__ pos)
{
    const int b = blockIdx.x, tid = threadIdx.x;
    float best = -3.0e38f; int bidx = 1 << 30;
    for (int m = tid; m < MM; m += 256) {
        const float v = rm[b * MM + m];
        if (v > best || (v == best && m < bidx)) { best = v; bidx = m; }
    }
#pragma unroll
    for (int msk = 1; msk < 64; msk <<= 1) {
        const float ov = __shfl_xor(best, msk);
        const int oi = __shfl_xor(bidx, msk);
        if (ov > best || (ov == best && oi < bidx)) { best = ov; bidx = oi; }
    }
    __shared__ float sv[4]; __shared__ int si[4];
    if ((tid & 63) == 0) { sv[tid >> 6] = best; si[tid >> 6] = bidx; }
    __syncthreads();
    if (tid == 0) {
        for (int w = 1; w < 4; ++w)
            if (sv[w] > best || (sv[w] == best && si[w] < bidx)) { best = sv[w]; bidx = si[w]; }
        pos[b] = bidx;
    }
}

// per batch: upd = tanh(relu([old,sel]@Wu1+bu1)@Wu2+bu2); write updated row
__global__ __launch_bounds__(256) void update_kernel(
    const float* __restrict__ mb, const float* __restrict__ ni,
    const float* __restrict__ Wu1, const float* __restrict__ bu1,
    const float* __restrict__ Wu2, const float* __restrict__ bu2,
    const float* __restrict__ wwp, const int* __restrict__ pos,
    const int* __restrict__ s_star, const int* __restrict__ exists,
    float* __restrict__ outu)
{
    const int b = blockIdx.x, tid = threadIdx.x;
    __shared__ float comb[2 * DD];
    __shared__ float hu[HH];
    const int p = pos[b], ss = s_star[b], ex = exists[b];
    const float* oldp = mb + ((size_t)(b * MM + p)) * DD;
    const float* selp = ni + ((size_t)(b * SS + ss)) * DD;
    for (int i = tid; i < DD; i += 256) { comb[i] = oldp[i]; comb[DD + i] = selp[i]; }
    __syncthreads();
#pragma unroll
    for (int t = 0; t < 2; ++t) {
        const int n = tid + t * 256;
        float a = bu1[n];
        for (int k = 0; k < 2 * DD; ++k) a = fmaf(comb[k], Wu1[(size_t)k * HH + n], a);
        hu[n] = fmaxf(a, 0.f);
    }
    __syncthreads();
#pragma unroll
    for (int t = 0; t < 2; ++t) {
        const int n = tid + t * 256;
        float a = bu2[n];
        for (int k = 0; k < HH; ++k) a = fmaf(hu[k], Wu2[(size_t)k * HH + n], a);
        const float upd = tanhf(a);
        const float wwv = wwp[((size_t)(b * MM + p)) * HH + n];
        const float ov = oldp[n];
        outu[((size_t)(b * MM + p)) * DD + n] = ex ? fmaf(upd, wwv, ov) : ov;
    }
}

extern "C" void kernel_launch(void* const* d_in, const int* in_sizes, int n_in,
                              void* d_out, int out_size, void* d_ws, size_t ws_size,
                              hipStream_t stream)
{
    const float* new_info    = (const float*)d_in[0];
    const float* memory_bank = (const float*)d_in[1];
    const float* W_in = (const float*)d_in[2];  const float* b_in = (const float*)d_in[3];
    const float* Wq   = (const float*)d_in[4];  const float* bq   = (const float*)d_in[5];
    const float* Wk   = (const float*)d_in[6];  const float* bk   = (const float*)d_in[7];
    const float* Wv   = (const float*)d_in[8];  const float* bv   = (const float*)d_in[9];
    const float* Wo   = (const float*)d_in[10]; const float* bo   = (const float*)d_in[11];
    const float* Wi1  = (const float*)d_in[12]; const float* bi1  = (const float*)d_in[13];
    const float* Wi2  = (const float*)d_in[14]; const float* bi2  = (const float*)d_in[15];
    const float* Wu1  = (const float*)d_in[16]; const float* bu1  = (const float*)d_in[17];
    const float* Wu2  = (const float*)d_in[18]; const float* bu2  = (const float*)d_in[19];

    float* out = (float*)d_out;
    float* out_updated = out;                               // B*M*D
    float* out_ww      = out + (size_t)BB * MM * HH;        // B*M*H
    float* out_imp     = out + 2 * (size_t)BB * MM * HH;    // B*S

    // workspace layout (f32 units), ~141 MB
    float* ws = (float*)d_ws;
    float* info_proj = ws;                                  // 4,194,304
    float* qhb       = info_proj + 4194304;                 // 8,388,608 (hidden1 aliases)
    float* ip_sp     = qhb + 8388608;                       // 4,194,304 (iph/ipl)
    float* mb_sp     = ip_sp + 4194304;                     // 8,388,608 (mbh/mbl; attn out reuses)
    float* kvreg     = mb_sp + 8388608;                     // 8,388,608 (K/V splits)
    float* winq      = kvreg + 8388608;                     // 262,144
    float* wtf       = winq + 262144;                       // 1,310,720 (us pairs)
    float* bq_eff    = wtf + 1310720;                       // 512
    float* bkv       = bq_eff + 512;                        // 1024
    float* rowmeanv  = bkv + 1024;                          // 16,384
    float* imp_mean  = rowmeanv + 16384;                    // 8
    int*   ipos      = (int*)(imp_mean + BB);
    int*   istar     = ipos + BB;
    int*   iexists   = istar + BB;

    float* hidden1 = qhb;  // B*S*256, dead before Q-GEMM writes qhb

    us* iph = (us*)ip_sp;          // [8192][512]
    us* ipl = iph + 4194304;
    us* mbh = (us*)mb_sp;          // [16384][512]
    us* mbl = mbh + 8388608;
    us* Kh  = (us*)kvreg;          // [8192][512]
    us* Kl  = Kh + 4194304;
    us* Vth = Kl + 4194304;        // [8][512][1024]
    us* Vtl = Vth + 4194304;

    us* wtq_h   = (us*)wtf;            us* wtq_l   = wtq_h + 262144;
    us* wtkv_h  = wtq_l + 262144;      us* wtkv_l  = wtkv_h + 524288;   // [1024][512]
    us* wto_h   = wtkv_l + 524288;     us* wto_l   = wto_h + 262144;
    us* wtinq_h = wto_l + 262144;      us* wtinq_l = wtinq_h + 262144;

    const dim3 blk(256);

    // updated := memory_bank copy + split (Q-GEMM A); tail zeros rowmeanv
    copy_split<<<dim3(2056), blk, 0, stream>>>(memory_bank, out_updated,
                                               mbh, mbl, 1048576, rowmeanv);

    // ---- weight prep: Wq, Wk|Wv (concat rows), Wo transposed+split
    TSB ts;
    ts.src[0] = Wq; ts.dh[0] = wtq_h;           ts.dl[0] = wtq_l;
    ts.src[1] = Wk; ts.dh[1] = wtkv_h;          ts.dl[1] = wtkv_l;
    ts.src[2] = Wv; ts.dh[2] = wtkv_h + 262144; ts.dl[2] = wtkv_l + 262144;
    ts.src[3] = Wo; ts.dh[3] = wto_h;           ts.dl[3] = wto_l;
    transpose_split_batch<<<dim3(16, 16, 4), blk, 0, stream>>>(ts);
    bias_prep<<<dim3(6), blk, 0, stream>>>(bk, bv, bkv, b_in, Wq, bq, bq_eff);

    // ---- importance path stays exact f32; epilogue also emits split for KV
    gemm128<<<dim3(4, 64), blk, 0, stream>>>(new_info, W_in, b_in, info_proj,
                                             DD, HH, 0, iph, ipl);
    gemm128<<<dim3(2, 64), blk, 0, stream>>>(info_proj, Wi1, bi1, hidden1,
                                             HH, HH / 2, 1, nullptr, nullptr);
    imp_kernel<<<dim3((BB * SS) / 4), blk, 0, stream>>>(hidden1, Wi2, bi2, out_imp);
    impstats_kernel<<<dim3(BB), blk, 0, stream>>>(out_imp, imp_mean, istar, iexists);

    // ---- fused Q weight: winq = W_in@Wq, then transpose+split
    gemm_mfma<<<dim3(4, 4), blk, 0, stream>>>(W_in, wtq_h, wtq_l,
                                              nullptr, winq, 512, 512);
    TSB ts2;
    ts2.src[0] = winq; ts2.dh[0] = wtinq_h; ts2.dl[0] = wtinq_l;
    transpose_split_batch<<<dim3(16, 16, 1), blk, 0, stream>>>(ts2);

    // ---- merged Q-GEMM + KV-GEMM (1024 blocks)
    gemm_qkv_ps<<<dim3(1024), blk, 0, stream>>>(mbh, mbl, wtinq_h, wtinq_l,
                                                bq_eff, qhb,
                                                iph, ipl, wtkv_h, wtkv_l, bkv,
                                                Kh, Kl, Vth, Vtl);

    // ---- MFMA flash attention -> pre-split output into mbh/mbl (dead now)
    attn_mfma<<<dim3(2048), blk, 0, stream>>>(qhb, Kh, Kl, Vth, Vtl, mbh, mbl);

    // ---- output projection + imp_mean rowscale + fused rowmean
    gemm_wo_ps<<<dim3(4, 128), blk, 0, stream>>>(mbh, mbl, wto_h, wto_l,
                                                 bo, out_ww, imp_mean, rowmeanv);

    // ---- slot selection + final row update
    argmax_kernel<<<dim3(BB), blk, 0, stream>>>(rowmeanv, ipos);
    update_kernel<<<dim3(BB), blk, 0, stream>>>(memory_bank, new_info,
                                                Wu1, bu1, Wu2, bu2, out_ww,
                                                ipos, istar, iexists, out_updated);
}

// Round 12
// 500.687 us; speedup vs baseline: 1.2070x; 1.1228x over previous
//
#include <hip/hip_runtime.h>
#include <hip/hip_bf16.h>
#include <math.h>

// Problem constants (AttentionWriter): B=8,S=1024,M=2048,D=512,H=512,NH=8,Dh=64
#define BB 8
#define SS 1024
#define MM 2048
#define DD 512
#define HH 512
#define NHEAD 8
#define DHEAD 64

typedef __attribute__((ext_vector_type(8))) short short8;
typedef __attribute__((ext_vector_type(4))) float f32x4;
typedef unsigned short us;

// bf16 split helpers — native cvt (v_cvt_pk_bf16_f32), RNE
__device__ __forceinline__ us bf_hi(float x) {
    __hip_bfloat16 h = __float2bfloat16(x);
    return *reinterpret_cast<const us*>(&h);
}
__device__ __forceinline__ float bf_f(us h) {
    return __uint_as_float(((unsigned)h) << 16);
}
__device__ __forceinline__ void split_pack4(float a, float b, float c, float d,
                                            uint2& hp, uint2& lp) {
    us h0 = bf_hi(a), h1 = bf_hi(b), h2 = bf_hi(c), h3 = bf_hi(d);
    hp.x = (unsigned)h0 | ((unsigned)h1 << 16);
    hp.y = (unsigned)h2 | ((unsigned)h3 << 16);
    us l0 = bf_hi(a - bf_f(h0)), l1 = bf_hi(b - bf_f(h1));
    us l2 = bf_hi(c - bf_f(h2)), l3 = bf_hi(d - bf_f(h3));
    lp.x = (unsigned)l0 | ((unsigned)l1 << 16);
    lp.y = (unsigned)l2 | ((unsigned)l3 << 16);
}

// async global->LDS DMA, 16B per lane; LDS dest = wave-uniform base + lane*16
__device__ __forceinline__ void gload_lds16(const void* g, void* l) {
    __builtin_amdgcn_global_load_lds(
        (__attribute__((address_space(1))) void*)(g),
        (__attribute__((address_space(3))) void*)(l), 16, 0, 0);
}

// ---------------------------------------------------------------------------
// merged prep: [0,2048) copy+split memory_bank; [2048,2056) zero rowmeanv;
// [2056,2060) bkv concat; [2060,2062) bq_eff = b_in@Wq + bq
// ---------------------------------------------------------------------------
__global__ __launch_bounds__(256) void prep_misc(
    const float* __restrict__ x, float* __restrict__ cpy,
    us* __restrict__ hi, us* __restrict__ lo, int n8, float* __restrict__ zbuf,
    const float* __restrict__ bk, const float* __restrict__ bv,
    float* __restrict__ bkv,
    const float* __restrict__ b_in, const float* __restrict__ Wq,
    const float* __restrict__ bq, float* __restrict__ bq_eff)
{
    const int blk = blockIdx.x, tid = threadIdx.x;
    if (blk >= 2060) {            // bq_eff
        const int n = (blk - 2060) * 256 + tid;
        float a = bq[n];
        for (int k = 0; k < 512; ++k) a = fmaf(b_in[k], Wq[(size_t)k * 512 + n], a);
        bq_eff[n] = a;
        return;
    }
    if (blk >= 2056) {            // bkv concat
        const int i = (blk - 2056) * 256 + tid;
        bkv[i] = (i < 512) ? bk[i] : bv[i - 512];
        return;
    }
    if (blk >= 2048) {            // zero rowmeanv
        const int i = (blk - 2048) * 2048 + tid * 8;
        *(float4*)(zbuf + i) = make_float4(0.f, 0.f, 0.f, 0.f);
        *(float4*)(zbuf + i + 4) = make_float4(0.f, 0.f, 0.f, 0.f);
        return;
    }
    const int stride = 2048 * 256;
    for (int i = blk * 256 + tid; i < n8; i += stride) {
        const float4 a = *(const float4*)(x + (size_t)i * 8);
        const float4 b = *(const float4*)(x + (size_t)i * 8 + 4);
        *(float4*)(cpy + (size_t)i * 8) = a;
        *(float4*)(cpy + (size_t)i * 8 + 4) = b;
        uint2 h0, l0, h1, l1;
        split_pack4(a.x, a.y, a.z, a.w, h0, l0);
        split_pack4(b.x, b.y, b.z, b.w, h1, l1);
        *(uint2*)(hi + (size_t)i * 8) = h0;
        *(uint2*)(hi + (size_t)i * 8 + 4) = h1;
        *(uint2*)(lo + (size_t)i * 8) = l0;
        *(uint2*)(lo + (size_t)i * 8 + 4) = l1;
    }
}

// ---------------------------------------------------------------------------
// batched transpose+split of [512][nc] f32 weights -> [nc][512] bf16 hi/lo
// ---------------------------------------------------------------------------
struct TSB {
    const float* src[6];
    us* dh[6];
    us* dl[6];
    int nc[6];
};
__global__ __launch_bounds__(256) void transpose_split_batch(TSB a)
{
    __shared__ float tile[32][33];
    const int tid = threadIdx.x;
    const int wsel = blockIdx.z;
    const int ncols = a.nc[wsel];
    const int n0 = blockIdx.x * 32, k0 = blockIdx.y * 32;
    if (n0 >= ncols) return;
    const float* W = a.src[wsel];
    {
        const int r = tid >> 3, c = (tid & 7) * 4;
        const float4 v = *(const float4*)(W + (size_t)(k0 + r) * ncols + n0 + c);
        tile[r][c + 0] = v.x; tile[r][c + 1] = v.y;
        tile[r][c + 2] = v.z; tile[r][c + 3] = v.w;
    }
    __syncthreads();
    {
        const int n = tid >> 3, k = (tid & 7) * 4;
        uint2 hp, lp;
        split_pack4(tile[k + 0][n], tile[k + 1][n], tile[k + 2][n], tile[k + 3][n], hp, lp);
        *(uint2*)(a.dh[wsel] + (size_t)(n0 + n) * 512 + k0 + k) = hp;
        *(uint2*)(a.dl[wsel] + (size_t)(n0 + n) * 512 + k0 + k) = lp;
    }
}

// ---------------------------------------------------------------------------
// split-bf16 MFMA GEMM, f32 A split in-kernel (winq + info_proj producers)
// ---------------------------------------------------------------------------
#define GEMM_F32A_BODY(K_)                                                          \
    __shared__ us sm[32768];                                                        \
    us* sAh = sm;            us* sAl = sm + 8192;                                   \
    us* sBh = sm + 16384;    us* sBl = sm + 24576;                                  \
    const int tid = threadIdx.x, lane = tid & 63;                                   \
    const int wid = tid >> 6, wm = wid >> 1, wn = wid & 1;                          \
    const int m0 = blockIdx.y * 128, n0 = blockIdx.x * 128;                         \
    const int fr = lane & 15, fq4 = lane >> 4;                                      \
    f32x4 acc[4][4];                                                                \
    _Pragma("unroll")                                                               \
    for (int i = 0; i < 4; ++i)                                                     \
        _Pragma("unroll")                                                           \
        for (int j = 0; j < 4; ++j)                                                 \
            _Pragma("unroll")                                                       \
            for (int r = 0; r < 4; ++r) acc[i][j][r] = 0.f;                         \
    const int ar = tid >> 4;                                                        \
    const int ak = (tid & 15) * 4;                                                  \
    int bsrow[4], bsf[4], bsoff[4];                                                 \
    _Pragma("unroll")                                                               \
    for (int it = 0; it < 4; ++it) {                                                \
        const int s = tid + 256 * it;                                               \
        bsrow[it] = s >> 3;                                                         \
        bsf[it] = s & 7;                                                            \
        bsoff[it] = bsrow[it] * 64 + ((bsf[it] ^ (bsrow[it] & 7)) << 3);            \
    }                                                                               \
    for (int k0 = 0; k0 < (K_); k0 += 64) {                                         \
        __syncthreads();                                                            \
        _Pragma("unroll")                                                           \
        for (int p = 0; p < 8; ++p) {                                               \
            const int r = p * 16 + ar;                                              \
            const float4 av = *(const float4*)(A + (size_t)(m0 + r) * (K_) + k0 + ak); \
            const int aoff = r * 128 + (((ak >> 3) ^ (r & 7)) << 4) + ((tid & 1) << 3); \
            uint2 hp, lp;                                                           \
            split_pack4(av.x, av.y, av.z, av.w, hp, lp);                            \
            *(uint2*)((char*)sAh + aoff) = hp;                                      \
            *(uint2*)((char*)sAl + aoff) = lp;                                      \
        }                                                                           \
        _Pragma("unroll")                                                           \
        for (int it = 0; it < 4; ++it) {                                            \
            const size_t bo = (size_t)(n0 + bsrow[it]) * (K_) + k0 + bsf[it] * 8;   \
            *(uint4*)(sBh + bsoff[it]) = *(const uint4*)(Bh + bo);                  \
            *(uint4*)(sBl + bsoff[it]) = *(const uint4*)(Bl + bo);                  \
        }                                                                           \
        __syncthreads();                                                            \
        _Pragma("unroll")                                                           \
        for (int ks = 0; ks < 2; ++ks) {                                            \
            short8 afh[4], afl[4], bfh[4], bfl[4];                                  \
            _Pragma("unroll")                                                       \
            for (int i = 0; i < 4; ++i) {                                           \
                const int row = wm * 64 + i * 16 + fr;                              \
                const int off = row * 128 + (((ks * 4 + fq4) ^ (row & 7)) << 4);    \
                afh[i] = *(const short8*)((const char*)sAh + off);                  \
                afl[i] = *(const short8*)((const char*)sAl + off);                  \
            }                                                                       \
            _Pragma("unroll")                                                       \
            for (int j = 0; j < 4; ++j) {                                           \
                const int row = wn * 64 + j * 16 + fr;                              \
                const int off = row * 128 + (((ks * 4 + fq4) ^ (row & 7)) << 4);    \
                bfh[j] = *(const short8*)((const char*)sBh + off);                  \
                bfl[j] = *(const short8*)((const char*)sBl + off);                  \
            }                                                                       \
            _Pragma("unroll")                                                       \
            for (int i = 0; i < 4; ++i)                                             \
                _Pragma("unroll")                                                   \
                for (int j = 0; j < 4; ++j) {                                       \
                    acc[i][j] = __builtin_amdgcn_mfma_f32_16x16x32_bf16(afh[i], bfh[j], acc[i][j], 0, 0, 0); \
                    acc[i][j] = __builtin_amdgcn_mfma_f32_16x16x32_bf16(afh[i], bfl[j], acc[i][j], 0, 0, 0); \
                    acc[i][j] = __builtin_amdgcn_mfma_f32_16x16x32_bf16(afl[i], bfh[j], acc[i][j], 0, 0, 0); \
                }                                                                   \
        }                                                                           \
    }

// winq = W_in@Wq (tiny, f32 C)
__global__ __launch_bounds__(256) void gemm_mfma(
    const float* __restrict__ A,
    const us* __restrict__ Bh, const us* __restrict__ Bl,
    float* __restrict__ C, int K, int N)
{
    GEMM_F32A_BODY(K)
#pragma unroll
    for (int j = 0; j < 4; ++j) {
        const int col = n0 + wn * 64 + j * 16 + fr;
#pragma unroll
        for (int i = 0; i < 4; ++i)
#pragma unroll
            for (int r = 0; r < 4; ++r) {
                const int row = m0 + wm * 64 + i * 16 + fq4 * 4 + r;
                C[(size_t)row * N + col] = acc[i][j][r];
            }
    }
}

// info_proj = new_info@W_in + b_in, emitted ONLY as pre-split bf16 hi/lo
__global__ __launch_bounds__(256) void gemm_mfma_info(
    const float* __restrict__ A,
    const us* __restrict__ Bh, const us* __restrict__ Bl,
    const float* __restrict__ bias,
    us* __restrict__ Oh, us* __restrict__ Ol)
{
    GEMM_F32A_BODY(512)
#pragma unroll
    for (int j = 0; j < 4; ++j) {
        const int col = n0 + wn * 64 + j * 16 + fr;
        const float bj = bias[col];
#pragma unroll
        for (int i = 0; i < 4; ++i)
#pragma unroll
            for (int r = 0; r < 4; ++r) {
                const int row = m0 + wm * 64 + i * 16 + fq4 * 4 + r;
                const float v = acc[i][j][r] + bj;
                const us hv = bf_hi(v);
                Oh[(size_t)row * 512 + col] = hv;
                Ol[(size_t)row * 512 + col] = bf_hi(v - bf_f(hv));
            }
    }
}

// ---------------------------------------------------------------------------
// PRE-SPLIT MFMA GEMM core (R9-validated DMA staging)
// ---------------------------------------------------------------------------
#define GEMM_PS_CORE(AhP, AlP, BhP, BlP, rsA_, K_)                                  \
    us* sAh = sm;            us* sAl = sm + 8192;                                   \
    us* sBh = sm + 16384;    us* sBl = sm + 24576;                                  \
    f32x4 acc[4][4];                                                                \
    _Pragma("unroll")                                                               \
    for (int i = 0; i < 4; ++i)                                                     \
        _Pragma("unroll")                                                           \
        for (int j = 0; j < 4; ++j)                                                 \
            _Pragma("unroll")                                                       \
            for (int r = 0; r < 4; ++r) acc[i][j][r] = 0.f;                         \
    const int fp = lane & 7, rsub = lane >> 3;                                      \
    const us* gsrc = (wid == 0) ? (AhP) : (wid == 1) ? (AlP)                        \
                   : (wid == 2) ? (BhP) : (BlP);                                    \
    const int grow0 = (wid < 2) ? m0 : n0;                                          \
    const int grs = (wid < 2) ? (rsA_) : (K_);                                      \
    us* lbase = sm + wid * 8192;                                                    \
    for (int k0 = 0; k0 < (K_); k0 += 64) {                                         \
        __syncthreads();                                                            \
        _Pragma("unroll")                                                           \
        for (int i = 0; i < 16; ++i) {                                              \
            const int row = i * 8 + rsub;                                           \
            const us* g = gsrc + (size_t)(grow0 + row) * grs + k0 +                 \
                          ((fp ^ (row & 7)) << 3);                                  \
            gload_lds16(g, lbase + i * 512);                                        \
        }                                                                           \
        __syncthreads();                                                            \
        _Pragma("unroll")                                                           \
        for (int ks = 0; ks < 2; ++ks) {                                            \
            short8 afh[4], afl[4], bfh[4], bfl[4];                                  \
            _Pragma("unroll")                                                       \
            for (int i = 0; i < 4; ++i) {                                           \
                const int row = wm * 64 + i * 16 + fr;                              \
                const int off = row * 128 + (((ks * 4 + fq4) ^ (row & 7)) << 4);    \
                afh[i] = *(const short8*)((const char*)sAh + off);                  \
                afl[i] = *(const short8*)((const char*)sAl + off);                  \
            }                                                                       \
            _Pragma("unroll")                                                       \
            for (int j = 0; j < 4; ++j) {                                           \
                const int row = wn * 64 + j * 16 + fr;                              \
                const int off = row * 128 + (((ks * 4 + fq4) ^ (row & 7)) << 4);    \
                bfh[j] = *(const short8*)((const char*)sBh + off);                  \
                bfl[j] = *(const short8*)((const char*)sBl + off);                  \
            }                                                                       \
            _Pragma("unroll")                                                       \
            for (int i = 0; i < 4; ++i)                                             \
                _Pragma("unroll")                                                   \
                for (int j = 0; j < 4; ++j) {                                       \
                    acc[i][j] = __builtin_amdgcn_mfma_f32_16x16x32_bf16(afh[i], bfh[j], acc[i][j], 0, 0, 0); \
                    acc[i][j] = __builtin_amdgcn_mfma_f32_16x16x32_bf16(afh[i], bfl[j], acc[i][j], 0, 0, 0); \
                    acc[i][j] = __builtin_amdgcn_mfma_f32_16x16x32_bf16(afl[i], bfh[j], acc[i][j], 0, 0, 0); \
                }                                                                   \
        }                                                                           \
    }

// hidden1 = relu(info_proj@Wi1 + bi1), f32 out; N=256, grid (2,64)
__global__ __launch_bounds__(256) void gemm_h1_ps(
    const us* __restrict__ Ah, const us* __restrict__ Al,
    const us* __restrict__ Bh, const us* __restrict__ Bl,
    const float* __restrict__ bias, float* __restrict__ C)
{
    __shared__ us sm[32768];
    const int tid = threadIdx.x, lane = tid & 63;
    const int wid = tid >> 6, wm = wid >> 1, wn = wid & 1;
    const int fr = lane & 15, fq4 = lane >> 4;
    const int m0 = blockIdx.y * 128, n0 = blockIdx.x * 128;
    GEMM_PS_CORE(Ah, Al, Bh, Bl, 512, 512)
#pragma unroll
    for (int j = 0; j < 4; ++j) {
        const int col = n0 + wn * 64 + j * 16 + fr;
        const float bj = bias[col];
#pragma unroll
        for (int i = 0; i < 4; ++i)
#pragma unroll
            for (int r = 0; r < 4; ++r) {
                const int row = m0 + wm * 64 + i * 16 + fq4 * 4 + r;
                C[(size_t)row * 256 + col] = fmaxf(acc[i][j][r] + bj, 0.f);
            }
    }
}

// merged Q-GEMM + KV-GEMM: 1024 blocks, id<512 -> Q tile, else KV tile.
__global__ __launch_bounds__(256) void gemm_qkv_ps(
    const us* __restrict__ mbh, const us* __restrict__ mbl,
    const us* __restrict__ wtinq_h, const us* __restrict__ wtinq_l,
    const float* __restrict__ bq_eff, float* __restrict__ qout,
    const us* __restrict__ iph, const us* __restrict__ ipl,
    const us* __restrict__ wtkv_h, const us* __restrict__ wtkv_l,
    const float* __restrict__ bkv,
    us* __restrict__ Kh, us* __restrict__ Kl,
    us* __restrict__ Vth, us* __restrict__ Vtl)
{
    __shared__ us sm[32768];
    const int tid = threadIdx.x, lane = tid & 63;
    const int wid = tid >> 6, wm = wid >> 1, wn = wid & 1;
    const int fr = lane & 15, fq4 = lane >> 4;
    const int id = blockIdx.x;
    const bool isQ = (id < 512);
    int m0, n0;
    const us *Ah, *Al, *Bh, *Bl;
    if (isQ) {
        m0 = (id >> 2) * 128; n0 = (id & 3) * 128;
        Ah = mbh; Al = mbl; Bh = wtinq_h; Bl = wtinq_l;
    } else {
        const int t = id - 512;
        m0 = (t >> 3) * 128; n0 = (t & 7) * 128;
        Ah = iph; Al = ipl; Bh = wtkv_h; Bl = wtkv_l;
    }
    GEMM_PS_CORE(Ah, Al, Bh, Bl, 512, 512)

    if (isQ) {
#pragma unroll
        for (int j = 0; j < 4; ++j) {
            const int col = n0 + wn * 64 + j * 16 + fr;
            const float bj = bq_eff[col];
#pragma unroll
            for (int i = 0; i < 4; ++i)
#pragma unroll
                for (int r = 0; r < 4; ++r) {
                    const int row = m0 + wm * 64 + i * 16 + fq4 * 4 + r;
                    qout[(size_t)row * 512 + col] = acc[i][j][r] + bj;
                }
        }
    } else if (n0 < 512) {
#pragma unroll
        for (int j = 0; j < 4; ++j) {
            const int col = n0 + wn * 64 + j * 16 + fr;
            const float bj = bkv[col];
#pragma unroll
            for (int i = 0; i < 4; ++i)
#pragma unroll
                for (int r = 0; r < 4; ++r) {
                    const int row = m0 + wm * 64 + i * 16 + fq4 * 4 + r;
                    const float v = acc[i][j][r] + bj;
                    const us hv = bf_hi(v);
                    Kh[(size_t)row * 512 + col] = hv;
                    Kl[(size_t)row * 512 + col] = bf_hi(v - bf_f(hv));
                }
        }
    } else {
#pragma unroll
        for (int j = 0; j < 4; ++j) {
            const int col = n0 + wn * 64 + j * 16 + fr;
            const float bj = bkv[col];
            const int d = col - 512;
#pragma unroll
            for (int i = 0; i < 4; ++i) {
                const int row0 = m0 + wm * 64 + i * 16 + fq4 * 4;
                uint2 hp, lp;
                split_pack4(acc[i][j][0] + bj, acc[i][j][1] + bj,
                            acc[i][j][2] + bj, acc[i][j][3] + bj, hp, lp);
                const size_t vo = ((size_t)(row0 >> 10) * 512 + d) * 1024 + (row0 & 1023);
                *(uint2*)(Vth + vo) = hp;
                *(uint2*)(Vtl + vo) = lp;
            }
        }
    }
}

// Wo-GEMM with fused rowmean
__global__ __launch_bounds__(256) void gemm_wo_ps(
    const us* __restrict__ Ah, const us* __restrict__ Al,
    const us* __restrict__ Bh, const us* __restrict__ Bl,
    const float* __restrict__ bias, float* __restrict__ C,
    const float* __restrict__ rowscale, float* __restrict__ rowmeanv)
{
    __shared__ us sm[32768];
    const int tid = threadIdx.x, lane = tid & 63;
    const int wid = tid >> 6, wm = wid >> 1, wn = wid & 1;
    const int fr = lane & 15, fq4 = lane >> 4;
    const int m0 = blockIdx.y * 128, n0 = blockIdx.x * 128;
    GEMM_PS_CORE(Ah, Al, Bh, Bl, 512, 512)

    float rsum[4][4];
#pragma unroll
    for (int i = 0; i < 4; ++i)
#pragma unroll
        for (int r = 0; r < 4; ++r) rsum[i][r] = 0.f;

#pragma unroll
    for (int j = 0; j < 4; ++j) {
        const int col = n0 + wn * 64 + j * 16 + fr;
        const float bj = bias[col];
#pragma unroll
        for (int i = 0; i < 4; ++i)
#pragma unroll
            for (int r = 0; r < 4; ++r) {
                const int row = m0 + wm * 64 + i * 16 + fq4 * 4 + r;
                const float v = (acc[i][j][r] + bj) * rowscale[row / MM];
                C[(size_t)row * 512 + col] = v;
                rsum[i][r] += v;
            }
    }

    __syncthreads();
    float* red = (float*)sm;
    if (tid < 128) red[tid] = 0.f;
    __syncthreads();
#pragma unroll
    for (int i = 0; i < 4; ++i)
#pragma unroll
        for (int r = 0; r < 4; ++r)
            atomicAdd(&red[wm * 64 + i * 16 + fq4 * 4 + r], rsum[i][r]);
    __syncthreads();
    if (tid < 128) atomicAdd(&rowmeanv[m0 + tid], red[tid] * (1.0f / 512.0f));
}

// ---------------------------------------------------------------------------
// MFMA flash attention (R9 structure): DMA-staged K/V, spill-free; epilogue
// emits pre-split hi/lo into mbh/mbl (dead after Q-GEMM).
// ---------------------------------------------------------------------------
__global__ __launch_bounds__(256) void attn_mfma(
    const float* __restrict__ qh,
    const us* __restrict__ Kh, const us* __restrict__ Kl,
    const us* __restrict__ Vth, const us* __restrict__ Vtl,
    us* __restrict__ aoh, us* __restrict__ aol)
{
    __shared__ us sm[24576];
    __shared__ float sSc[64];
    us* sKh = sm;            us* sKl = sm + 4096;
    us* sVh = sm + 8192;     us* sVl = sm + 12288;
    us* sPh = sm + 16384;    us* sPl = sm + 20480;

    const int tid = threadIdx.x, lane = tid & 63, w = tid >> 6;
    const int fr = lane & 15, fq4 = lane >> 4;

    const int wg = blockIdx.x;
    const int xcd = wg & 7, ix = wg >> 3;
    const int mt = ix & 31;
    const int pair = xcd + 8 * (ix >> 5);
    const int h = pair & 7, b = pair >> 3;
    const int m0 = mt * 64;

    const float* Qg = qh + ((size_t)(b * MM + m0)) * HH + h * DHEAD;
    const us* Kgh = Kh + ((size_t)b * SS) * 512 + h * DHEAD;
    const us* Kgl = Kl + ((size_t)b * SS) * 512 + h * DHEAD;
    const us* Vgh = Vth + ((size_t)b * 512 + h * DHEAD) * 1024;
    const us* Vgl = Vtl + ((size_t)b * 512 + h * DHEAD) * 1024;
    us* Oh = aoh + ((size_t)(b * MM + m0)) * 512 + h * DHEAD;
    us* Ol = aol + ((size_t)(b * MM + m0)) * 512 + h * DHEAD;

    short8 qfh[2], qfl[2];
#pragma unroll
    for (int ks = 0; ks < 2; ++ks) {
        const float* qp = Qg + (size_t)(w * 16 + fr) * HH + ks * 32 + fq4 * 8;
        const float4 u0 = *(const float4*)qp;
        const float4 u1 = *(const float4*)(qp + 4);
        float v[8] = {u0.x, u0.y, u0.z, u0.w, u1.x, u1.y, u1.z, u1.w};
#pragma unroll
        for (int e = 0; e < 8; ++e) {
            const float x = v[e] * 0.125f;
            const us hb = bf_hi(x);
            qfh[ks][e] = (short)hb;
            qfl[ks][e] = (short)bf_hi(x - bf_f(hb));
        }
    }

    const int fp = lane & 7;
    const int rsub = lane >> 3;
    const bool isK = (w < 2);
    const us* gA = (w == 0) ? Kgh : (w == 1) ? Kgl : (w == 2) ? Vgh : Vgl;
    us* lbase = sm + w * 4096;

    f32x4 oacc[4];
#pragma unroll
    for (int j = 0; j < 4; ++j)
#pragma unroll
        for (int r = 0; r < 4; ++r) oacc[j][r] = 0.f;
    float mrun = -1e30f, lrun = 0.f;

    for (int t = 0; t < SS / 64; ++t) {
        __syncthreads();
        if (isK) {
#pragma unroll
            for (int i = 0; i < 8; ++i) {
                const int row = i * 8 + rsub;
                const us* g = gA + (size_t)(t * 64 + row) * 512 + ((fp ^ (row & 7)) << 3);
                gload_lds16(g, lbase + i * 512);
            }
        } else {
#pragma unroll
            for (int i = 0; i < 8; ++i) {
                const int row = i * 8 + rsub;
                const us* g = gA + (size_t)row * 1024 + t * 64 + ((fp ^ (row & 7)) << 3);
                gload_lds16(g, lbase + i * 512);
            }
        }
        __syncthreads();

        f32x4 stt[4];
#pragma unroll
        for (int fs = 0; fs < 4; ++fs)
#pragma unroll
            for (int r = 0; r < 4; ++r) stt[fs][r] = 0.f;
#pragma unroll
        for (int ks = 0; ks < 2; ++ks) {
            short8 kfh[4], kfl[4];
#pragma unroll
            for (int fs = 0; fs < 4; ++fs) {
                const int row = fs * 16 + fr;
                const int off = row * 128 + (((ks * 4 + fq4) ^ (row & 7)) << 4);
                kfh[fs] = *(const short8*)((const char*)sKh + off);
                kfl[fs] = *(const short8*)((const char*)sKl + off);
            }
#pragma unroll
            for (int fs = 0; fs < 4; ++fs) {
                stt[fs] = __builtin_amdgcn_mfma_f32_16x16x32_bf16(kfh[fs], qfh[ks], stt[fs], 0, 0, 0);
                stt[fs] = __builtin_amdgcn_mfma_f32_16x16x32_bf16(kfh[fs], qfl[ks], stt[fs], 0, 0, 0);
                stt[fs] = __builtin_amdgcn_mfma_f32_16x16x32_bf16(kfl[fs], qfh[ks], stt[fs], 0, 0, 0);
            }
        }

        {
            float mx = stt[0][0];
#pragma unroll
            for (int fs = 0; fs < 4; ++fs)
#pragma unroll
                for (int r = 0; r < 4; ++r) mx = fmaxf(mx, stt[fs][r]);
            mx = fmaxf(mx, __shfl_xor(mx, 16));
            mx = fmaxf(mx, __shfl_xor(mx, 32));
            const float nm = fmaxf(mrun, mx);
            const float scf = __expf(mrun - nm);
            mrun = nm;
            float ps = 0.f;
#pragma unroll
            for (int fs = 0; fs < 4; ++fs)
#pragma unroll
                for (int r = 0; r < 4; ++r) {
                    const float p = __expf(stt[fs][r] - nm);
                    stt[fs][r] = p;
                    ps += p;
                }
            ps += __shfl_xor(ps, 16);
            ps += __shfl_xor(ps, 32);
            lrun = lrun * scf + ps;
            if (fq4 == 0) sSc[w * 16 + fr] = scf;
        }

#pragma unroll
        for (int fs = 0; fs < 4; ++fs) {
            const int q = w * 16 + fr;
            const int flog = (fs << 1) | (fq4 >> 1);
            const int off = q * 128 + ((flog ^ (q & 7)) << 4) + ((fq4 & 1) << 3);
            uint2 hp, lp;
            split_pack4(stt[fs][0], stt[fs][1], stt[fs][2], stt[fs][3], hp, lp);
            *(uint2*)((char*)sPh + off) = hp;
            *(uint2*)((char*)sPl + off) = lp;
        }

#pragma unroll
        for (int r = 0; r < 4; ++r) {
            const float scv = sSc[w * 16 + fq4 * 4 + r];
#pragma unroll
            for (int fd = 0; fd < 4; ++fd) oacc[fd][r] *= scv;
        }

#pragma unroll
        for (int ks = 0; ks < 2; ++ks) {
            short8 pfh, pfl, vfh[4], vfl[4];
            {
                const int row = w * 16 + fr;
                const int off = row * 128 + (((ks * 4 + fq4) ^ (row & 7)) << 4);
                pfh = *(const short8*)((const char*)sPh + off);
                pfl = *(const short8*)((const char*)sPl + off);
            }
#pragma unroll
            for (int fd = 0; fd < 4; ++fd) {
                const int row = fd * 16 + fr;
                const int off = row * 128 + (((ks * 4 + fq4) ^ (row & 7)) << 4);
                vfh[fd] = *(const short8*)((const char*)sVh + off);
                vfl[fd] = *(const short8*)((const char*)sVl + off);
            }
#pragma unroll
            for (int fd = 0; fd < 4; ++fd) {
                oacc[fd] = __builtin_amdgcn_mfma_f32_16x16x32_bf16(pfh, vfh[fd], oacc[fd], 0, 0, 0);
                oacc[fd] = __builtin_amdgcn_mfma_f32_16x16x32_bf16(pfh, vfl[fd], oacc[fd], 0, 0, 0);
                oacc[fd] = __builtin_amdgcn_mfma_f32_16x16x32_bf16(pfl, vfh[fd], oacc[fd], 0, 0, 0);
            }
        }
    }

    if (fq4 == 0) sSc[w * 16 + fr] = lrun;
#pragma unroll
    for (int r = 0; r < 4; ++r) {
        const float inv = 1.0f / sSc[w * 16 + fq4 * 4 + r];
        const int q = w * 16 + fq4 * 4 + r;
#pragma unroll
        for (int fd = 0; fd < 4; ++fd) {
            const float v = oacc[fd][r] * inv;
            const us hv = bf_hi(v);
            Oh[(size_t)q * 512 + fd * 16 + fr] = hv;
            Ol[(size_t)q * 512 + fd * 16 + fr] = bf_hi(v - bf_f(hv));
        }
    }
}

// imp[row] = sigmoid(dot(h1[row,0:256], Wi2) + bi2); one wave per row
__global__ __launch_bounds__(256) void imp_kernel(
    const float* __restrict__ h1, const float* __restrict__ Wi2,
    const float* __restrict__ bi2, float* __restrict__ imp)
{
    const int wv = threadIdx.x >> 6, lane = threadIdx.x & 63;
    const int row = blockIdx.x * 4 + wv;
    const float4 hv = *(const float4*)(h1 + (size_t)row * 256 + lane * 4);
    const float4 wvv = *(const float4*)(Wi2 + lane * 4);
    float s = hv.x * wvv.x + hv.y * wvv.y + hv.z * wvv.z + hv.w * wvv.w;
#pragma unroll
    for (int m = 1; m < 64; m <<= 1) s += __shfl_xor(s, m);
    if (lane == 0) imp[row] = 1.0f / (1.0f + expf(-(s + bi2[0])));
}

// per batch: mean(imp), last index with imp>0.5, exists
__global__ __launch_bounds__(256) void impstats_kernel(
    const float* __restrict__ imp, float* __restrict__ imp_mean,
    int* __restrict__ s_star, int* __restrict__ exists)
{
    const int b = blockIdx.x, tid = threadIdx.x;
    float sum = 0.f; int last = -1;
    for (int s = tid; s < SS; s += 256) {
        const float v = imp[b * SS + s];
        sum += v;
        if (v > 0.5f) last = s;
    }
#pragma unroll
    for (int m = 1; m < 64; m <<= 1) {
        sum += __shfl_xor(sum, m);
        last = max(last, __shfl_xor(last, m));
    }
    __shared__ float ssum[4]; __shared__ int slast[4];
    if ((tid & 63) == 0) { ssum[tid >> 6] = sum; slast[tid >> 6] = last; }
    __syncthreads();
    if (tid == 0) {
        const float t = ssum[0] + ssum[1] + ssum[2] + ssum[3];
        const int ml = max(max(slast[0], slast[1]), max(slast[2], slast[3]));
        imp_mean[b] = t / (float)SS;
        exists[b] = (ml >= 0) ? 1 : 0;
        s_star[b] = (ml >= 0) ? ml : (SS - 1);
    }
}

// per batch: first-occurrence argmax over M rowmeans
__global__ __launch_bounds__(256) void argmax_kernel(
    const float* __restrict__ rm, int* __restrict__ pos)
{
    const int b = blockIdx.x, tid = threadIdx.x;
    float best = -3.0e38f; int bidx = 1 << 30;
    for (int m = tid; m < MM; m += 256) {
        const float v = rm[b * MM + m];
        if (v > best || (v == best && m < bidx)) { best = v; bidx = m; }
    }
#pragma unroll
    for (int msk = 1; msk < 64; msk <<= 1) {
        const float ov = __shfl_xor(best, msk);
        const int oi = __shfl_xor(bidx, msk);
        if (ov > best || (ov == best && oi < bidx)) { best = ov; bidx = oi; }
    }
    __shared__ float sv[4]; __shared__ int si[4];
    if ((tid & 63) == 0) { sv[tid >> 6] = best; si[tid >> 6] = bidx; }
    __syncthreads();
    if (tid == 0) {
        for (int w = 1; w < 4; ++w)
            if (sv[w] > best || (sv[w] == best && si[w] < bidx)) { best = sv[w]; bidx = si[w]; }
        pos[b] = bidx;
    }
}

// per batch: upd = tanh(relu([old,sel]@Wu1+bu1)@Wu2+bu2); write updated row
__global__ __launch_bounds__(256) void update_kernel(
    const float* __restrict__ mb, const float* __restrict__ ni,
    const float* __restrict__ Wu1, const float* __restrict__ bu1,
    const float* __restrict__ Wu2, const float* __restrict__ bu2,
    const float* __restrict__ wwp, const int* __restrict__ pos,
    const int* __restrict__ s_star, const int* __restrict__ exists,
    float* __restrict__ outu)
{
    const int b = blockIdx.x, tid = threadIdx.x;
    __shared__ float comb[2 * DD];
    __shared__ float hu[HH];
    const int p = pos[b], ss = s_star[b], ex = exists[b];
    const float* oldp = mb + ((size_t)(b * MM + p)) * DD;
    const float* selp = ni + ((size_t)(b * SS + ss)) * DD;
    for (int i = tid; i < DD; i += 256) { comb[i] = oldp[i]; comb[DD + i] = selp[i]; }
    __syncthreads();
#pragma unroll
    for (int t = 0; t < 2; ++t) {
        const int n = tid + t * 256;
        float a = bu1[n];
        for (int k = 0; k < 2 * DD; ++k) a = fmaf(comb[k], Wu1[(size_t)k * HH + n], a);
        hu[n] = fmaxf(a, 0.f);
    }
    __syncthreads();
#pragma unroll
    for (int t = 0; t < 2; ++t) {
        const int n = tid + t * 256;
        float a = bu2[n];
        for (int k = 0; k < HH; ++k) a = fmaf(hu[k], Wu2[(size_t)k * HH + n], a);
        const float upd = tanhf(a);
        const float wwv = wwp[((size_t)(b * MM + p)) * HH + n];
        const float ov = oldp[n];
        outu[((size_t)(b * MM + p)) * DD + n] = ex ? fmaf(upd, wwv, ov) : ov;
    }
}

extern "C" void kernel_launch(void* const* d_in, const int* in_sizes, int n_in,
                              void* d_out, int out_size, void* d_ws, size_t ws_size,
                              hipStream_t stream)
{
    const float* new_info    = (const float*)d_in[0];
    const float* memory_bank = (const float*)d_in[1];
    const float* W_in = (const float*)d_in[2];  const float* b_in = (const float*)d_in[3];
    const float* Wq   = (const float*)d_in[4];  const float* bq   = (const float*)d_in[5];
    const float* Wk   = (const float*)d_in[6];  const float* bk   = (const float*)d_in[7];
    const float* Wv   = (const float*)d_in[8];  const float* bv   = (const float*)d_in[9];
    const float* Wo   = (const float*)d_in[10]; const float* bo   = (const float*)d_in[11];
    const float* Wi1  = (const float*)d_in[12]; const float* bi1  = (const float*)d_in[13];
    const float* Wi2  = (const float*)d_in[14]; const float* bi2  = (const float*)d_in[15];
    const float* Wu1  = (const float*)d_in[16]; const float* bu1  = (const float*)d_in[17];
    const float* Wu2  = (const float*)d_in[18]; const float* bu2  = (const float*)d_in[19];

    float* out = (float*)d_out;
    float* out_updated = out;                               // B*M*D
    float* out_ww      = out + (size_t)BB * MM * HH;        // B*M*H
    float* out_imp     = out + 2 * (size_t)BB * MM * HH;    // B*S

    // workspace layout (f32 units), ~140 MB
    float* ws = (float*)d_ws;
    float* qhb       = ws;                                  // 8,388,608 (hidden1 aliases)
    float* ip_sp     = qhb + 8388608;                       // 4,194,304 (iph/ipl)
    float* mb_sp     = ip_sp + 4194304;                     // 8,388,608 (mbh/mbl; attn out reuses)
    float* kvreg     = mb_sp + 8388608;                     // 8,388,608 (K/V splits)
    float* winq      = kvreg + 8388608;                     // 262,144
    float* wtf       = winq + 262144;                       // 1,703,936 (us pairs)
    float* bq_eff    = wtf + 1703936;                       // 512
    float* bkv       = bq_eff + 512;                        // 1024
    float* rowmeanv  = bkv + 1024;                          // 16,384
    float* imp_mean  = rowmeanv + 16384;                    // 8
    int*   ipos      = (int*)(imp_mean + BB);
    int*   istar     = ipos + BB;
    int*   iexists   = istar + BB;

    float* hidden1 = qhb;  // B*S*256, dead before Q-GEMM writes qhb

    us* iph = (us*)ip_sp;          // [8192][512]
    us* ipl = iph + 4194304;
    us* mbh = (us*)mb_sp;          // [16384][512]
    us* mbl = mbh + 8388608;
    us* Kh  = (us*)kvreg;          // [8192][512]
    us* Kl  = Kh + 4194304;
    us* Vth = Kl + 4194304;        // [8][512][1024]
    us* Vtl = Vth + 4194304;

    us* wtin_h  = (us*)wtf;            us* wtin_l  = wtin_h + 262144;
    us* wtq_h   = wtin_l + 262144;     us* wtq_l   = wtq_h + 262144;
    us* wtkv_h  = wtq_l + 262144;      us* wtkv_l  = wtkv_h + 524288;   // [1024][512]
    us* wto_h   = wtkv_l + 524288;     us* wto_l   = wto_h + 262144;
    us* wtinq_h = wto_l + 262144;      us* wtinq_l = wtinq_h + 262144;
    us* wti1_h  = wtinq_l + 262144;    us* wti1_l  = wti1_h + 131072;   // [256][512]

    const dim3 blk(256);

    // merged prep: mb copy+split, rowmeanv zero, bkv, bq_eff
    prep_misc<<<dim3(2062), blk, 0, stream>>>(memory_bank, out_updated,
                                              mbh, mbl, 1048576, rowmeanv,
                                              bk, bv, bkv, b_in, Wq, bq, bq_eff);

    // weight prep: W_in, Wq, Wk|Wv, Wo, Wi1 transposed+split (one launch)
    TSB ts;
    ts.src[0] = W_in; ts.dh[0] = wtin_h;          ts.dl[0] = wtin_l;          ts.nc[0] = 512;
    ts.src[1] = Wq;   ts.dh[1] = wtq_h;           ts.dl[1] = wtq_l;           ts.nc[1] = 512;
    ts.src[2] = Wk;   ts.dh[2] = wtkv_h;          ts.dl[2] = wtkv_l;          ts.nc[2] = 512;
    ts.src[3] = Wv;   ts.dh[3] = wtkv_h + 262144; ts.dl[3] = wtkv_l + 262144; ts.nc[3] = 512;
    ts.src[4] = Wo;   ts.dh[4] = wto_h;           ts.dl[4] = wto_l;           ts.nc[4] = 512;
    ts.src[5] = Wi1;  ts.dh[5] = wti1_h;          ts.dl[5] = wti1_l;          ts.nc[5] = 256;
    transpose_split_batch<<<dim3(16, 16, 6), blk, 0, stream>>>(ts);

    // info_proj (pre-split only) via MFMA; importance MLP via _ps MFMA + f32 tail
    gemm_mfma_info<<<dim3(4, 64), blk, 0, stream>>>(new_info, wtin_h, wtin_l,
                                                    b_in, iph, ipl);
    gemm_h1_ps<<<dim3(2, 64), blk, 0, stream>>>(iph, ipl, wti1_h, wti1_l,
                                                bi1, hidden1);
    imp_kernel<<<dim3((BB * SS) / 4), blk, 0, stream>>>(hidden1, Wi2, bi2, out_imp);
    impstats_kernel<<<dim3(BB), blk, 0, stream>>>(out_imp, imp_mean, istar, iexists);

    // fused Q weight: winq = W_in@Wq, then transpose+split
    gemm_mfma<<<dim3(4, 4), blk, 0, stream>>>(W_in, wtq_h, wtq_l, winq, 512, 512);
    TSB ts2;
    ts2.src[0] = winq; ts2.dh[0] = wtinq_h; ts2.dl[0] = wtinq_l; ts2.nc[0] = 512;
    transpose_split_batch<<<dim3(16, 16, 1), blk, 0, stream>>>(ts2);

    // merged Q-GEMM + KV-GEMM (1024 blocks)
    gemm_qkv_ps<<<dim3(1024), blk, 0, stream>>>(mbh, mbl, wtinq_h, wtinq_l,
                                                bq_eff, qhb,
                                                iph, ipl, wtkv_h, wtkv_l, bkv,
                                                Kh, Kl, Vth, Vtl);

    // MFMA flash attention -> pre-split output into mbh/mbl (dead now)
    attn_mfma<<<dim3(2048), blk, 0, stream>>>(qhb, Kh, Kl, Vth, Vtl, mbh, mbl);

    // output projection + imp_mean rowscale + fused rowmean
    gemm_wo_ps<<<dim3(4, 128), blk, 0, stream>>>(mbh, mbl, wto_h, wto_l,
                                                 bo, out_ww, imp_mean, rowmeanv);

    // slot selection + final row update
    argmax_kernel<<<dim3(BB), blk, 0, stream>>>(rowmeanv, ipos);
    update_kernel<<<dim3(BB), blk, 0, stream>>>(memory_bank, new_info,
                                                Wu1, bu1, Wu2, bu2, out_ww,
                                                ipos, istar, iexists, out_updated);
}